// Round 1
// baseline (1632.578 us; speedup 1.0000x reference)
//
#include <hip/hip_runtime.h>

#define BATCH      4096
#define OBS_COLS   2304
#define OTH_OFF    2048
#define NOBJ       64
#define DOBJ       32
#define PIIN       31
#define EMB        256
#define NH         4
#define HD         64
#define OUTC       512

// ---------------------------------------------------------------------------
// Kernel 1: others_e = relu(others@oW1+ob1)@oW2+ob2  -> d_out[b*512 + 0..255]
// 8 batch rows per workgroup (weight reuse x8), thread j = output column.
// ---------------------------------------------------------------------------
__global__ __launch_bounds__(256, 2) void k_others(
    const float* __restrict__ obs,
    const float* __restrict__ oW1, const float* __restrict__ ob1,
    const float* __restrict__ oW2, const float* __restrict__ ob2,
    float* __restrict__ out)
{
    __shared__ float s_in[8][256];
    __shared__ float s_t[8][256];
    const int j  = threadIdx.x;
    const int b0 = blockIdx.x * 8;

    #pragma unroll
    for (int r = 0; r < 8; ++r)
        s_in[r][j] = obs[(size_t)(b0 + r) * OBS_COLS + OTH_OFF + j];
    __syncthreads();

    float acc[8];
    // layer 1
    {
        const float bias = ob1[j];
        #pragma unroll
        for (int r = 0; r < 8; ++r) acc[r] = bias;
        for (int i = 0; i < 256; i += 4) {
            const float w0 = oW1[(i + 0) * 256 + j];
            const float w1 = oW1[(i + 1) * 256 + j];
            const float w2 = oW1[(i + 2) * 256 + j];
            const float w3 = oW1[(i + 3) * 256 + j];
            #pragma unroll
            for (int r = 0; r < 8; ++r) {
                const float4 v = *(const float4*)&s_in[r][i];
                acc[r] += v.x * w0 + v.y * w1 + v.z * w2 + v.w * w3;
            }
        }
        #pragma unroll
        for (int r = 0; r < 8; ++r) s_t[r][j] = fmaxf(acc[r], 0.0f);
    }
    __syncthreads();
    // layer 2
    {
        const float bias = ob2[j];
        #pragma unroll
        for (int r = 0; r < 8; ++r) acc[r] = bias;
        for (int i = 0; i < 256; i += 4) {
            const float w0 = oW2[(i + 0) * 256 + j];
            const float w1 = oW2[(i + 1) * 256 + j];
            const float w2 = oW2[(i + 2) * 256 + j];
            const float w3 = oW2[(i + 3) * 256 + j];
            #pragma unroll
            for (int r = 0; r < 8; ++r) {
                const float4 v = *(const float4*)&s_t[r][i];
                acc[r] += v.x * w0 + v.y * w1 + v.z * w2 + v.w * w3;
            }
        }
        #pragma unroll
        for (int r = 0; r < 8; ++r)
            out[(size_t)(b0 + r) * OUTC + j] = acc[r];
    }
}

// ---------------------------------------------------------------------------
// Kernel 2: per batch row b (one WG, 512 threads):
//   emb = obj-MLP(feats)*mask  (64x256 tile kept in LDS, reg round-trip)
//   q   = others_e@Wq+bq  (others_e read back from d_out)
//   logits via qk[h]=Wk[h]·q[h] fold; wave-level softmax (wave == head)
//   out_emb via Wv fold: out = Wv[h]^T·(Σ_n attn·mask·emb_n) + (Σ attn·mask)·bv
// ---------------------------------------------------------------------------
__global__ __launch_bounds__(512, 4) void k_objattn(
    const float* __restrict__ obs,
    const float* __restrict__ pW1, const float* __restrict__ pb1,
    const float* __restrict__ pW2, const float* __restrict__ pb2,
    const float* __restrict__ pW3, const float* __restrict__ pb3,
    const float* __restrict__ Wq,  const float* __restrict__ bq,
    const float* __restrict__ Wk,  const float* __restrict__ bk,
    const float* __restrict__ Wv,  const float* __restrict__ bv,
    float* __restrict__ out)
{
    __shared__ __align__(16) float s_obj[NOBJ * DOBJ];   // 8 KB (feats + mask col)
    __shared__ __align__(16) float s_h[NOBJ * EMB];      // 64 KB (h1 -> h2 -> emb -> val-free)
    __shared__ __align__(16) float s_oe[EMB];
    __shared__ __align__(16) float s_q[EMB];
    __shared__ __align__(16) float s_x[EMB];             // qk, then p (attn-weighted emb)
    __shared__ float s_am[NH * NOBJ];                    // attn * mask
    __shared__ float s_amsum[NH];

    const int t  = threadIdx.x;
    const int b  = blockIdx.x;
    const int j  = t & 255;      // output column for the GEMMs
    const int ng = t >> 8;       // row-group 0/1
    const int n0 = ng * 32;

    const float* obs_b = obs + (size_t)b * OBS_COLS;

    // stage objects (64x32) and others_e (from kernel 1's output)
    if (t < 512) {
        ((float4*)s_obj)[t] = ((const float4*)obs_b)[t];
    }
    if (t < 64) {
        ((float4*)s_oe)[t] = ((const float4*)(out + (size_t)b * OUTC))[t];
    }
    __syncthreads();

    // ---- q = others_e @ Wq + bq  (threads 0..255, col t) ----
    if (t < 256) {
        float a = bq[t];
        for (int i = 0; i < 256; i += 4) {
            const float4 v = *(const float4*)&s_oe[i];
            a += v.x * Wq[(i + 0) * 256 + t] + v.y * Wq[(i + 1) * 256 + t]
               + v.z * Wq[(i + 2) * 256 + t] + v.w * Wq[(i + 3) * 256 + t];
        }
        s_q[t] = a;
    }

    // ---- GEMM1: h1 = relu(feats @ pW1 + pb1), K=31 ----
    {
        float acc[32];
        const float bias = pb1[j];
        #pragma unroll
        for (int r = 0; r < 32; ++r) acc[r] = bias;
        for (int k = 0; k < PIIN; ++k) {
            const float w = pW1[k * 256 + j];
            #pragma unroll
            for (int r = 0; r < 32; ++r)
                acc[r] += s_obj[(n0 + r) * DOBJ + k] * w;
        }
        #pragma unroll
        for (int r = 0; r < 32; ++r)
            s_h[(n0 + r) * EMB + j] = fmaxf(acc[r], 0.0f);
    }
    __syncthreads();

    // ---- qk[h][d] = sum_e q[h][e] * Wk[h][d][e]  (t<256: h=t>>6, d=t&63) ----
    if (t < 256) {
        const int h = t >> 6, d = t & 63;
        const float* w = &Wk[(size_t)h * HD * HD + (size_t)d * HD];
        float a = 0.0f;
        for (int e = 0; e < HD; e += 4) {
            const float4 qv = *(const float4*)&s_q[h * HD + e];
            a += qv.x * w[e + 0] + qv.y * w[e + 1] + qv.z * w[e + 2] + qv.w * w[e + 3];
        }
        s_x[t] = a;
    }

    // ---- GEMM2: h2 = relu(h1 @ pW2 + pb2), K=256 ----
    {
        float acc[32];
        const float bias = pb2[j];
        #pragma unroll
        for (int r = 0; r < 32; ++r) acc[r] = bias;
        for (int k = 0; k < EMB; k += 4) {
            const float w0 = pW2[(k + 0) * 256 + j];
            const float w1 = pW2[(k + 1) * 256 + j];
            const float w2 = pW2[(k + 2) * 256 + j];
            const float w3 = pW2[(k + 3) * 256 + j];
            #pragma unroll
            for (int r = 0; r < 32; ++r) {
                const float4 v = *(const float4*)&s_h[(n0 + r) * EMB + k];
                acc[r] += v.x * w0 + v.y * w1 + v.z * w2 + v.w * w3;
            }
        }
        __syncthreads();   // everyone done reading h1
        #pragma unroll
        for (int r = 0; r < 32; ++r)
            s_h[(n0 + r) * EMB + j] = fmaxf(acc[r], 0.0f);
    }
    __syncthreads();

    // ---- GEMM3: emb = (h2 @ pW3 + pb3) * mask, K=256 ----
    {
        float acc[32];
        const float bias = pb3[j];
        #pragma unroll
        for (int r = 0; r < 32; ++r) acc[r] = bias;
        for (int k = 0; k < EMB; k += 4) {
            const float w0 = pW3[(k + 0) * 256 + j];
            const float w1 = pW3[(k + 1) * 256 + j];
            const float w2 = pW3[(k + 2) * 256 + j];
            const float w3 = pW3[(k + 3) * 256 + j];
            #pragma unroll
            for (int r = 0; r < 32; ++r) {
                const float4 v = *(const float4*)&s_h[(n0 + r) * EMB + k];
                acc[r] += v.x * w0 + v.y * w1 + v.z * w2 + v.w * w3;
            }
        }
        __syncthreads();   // everyone done reading h2
        #pragma unroll
        for (int r = 0; r < 32; ++r)
            s_h[(n0 + r) * EMB + j] = acc[r] * s_obj[(n0 + r) * DOBJ + 31];
    }
    __syncthreads();

    // ---- logits + softmax (t<256: wave == head h, lane == object n) ----
    if (t < 256) {
        const int h = t >> 6, n = t & 63;
        // qb[h] = sum_e q[h][e]*bk[h][e] via wave butterfly (lane acts as e)
        float qb = s_q[h * HD + n] * bk[h * HD + n];
        #pragma unroll
        for (int off = 32; off > 0; off >>= 1)
            qb += __shfl_xor(qb, off, 64);
        float dotv = 0.0f;
        for (int d = 0; d < HD; d += 4) {
            const float4 ev = *(const float4*)&s_h[n * EMB + h * HD + d];
            const float4 kv = *(const float4*)&s_x[h * HD + d];
            dotv += ev.x * kv.x + ev.y * kv.y + ev.z * kv.z + ev.w * kv.w;
        }
        const float mask = s_obj[n * DOBJ + 31];
        float logit = (dotv + qb) * 0.0625f;       // / sqrt(EMB) = /16
        if (mask == 0.0f) logit = -1.0e9f;
        float m = logit;
        #pragma unroll
        for (int off = 32; off > 0; off >>= 1)
            m = fmaxf(m, __shfl_xor(m, off, 64));
        const float ex = __expf(logit - m);
        float s = ex;
        #pragma unroll
        for (int off = 32; off > 0; off >>= 1)
            s += __shfl_xor(s, off, 64);
        const float attn = ex / s;
        const float am   = attn * mask;            // fold val's mask factor
        s_am[t] = am;
        float ams = am;
        #pragma unroll
        for (int off = 32; off > 0; off >>= 1)
            ams += __shfl_xor(ams, off, 64);
        if (n == 0) s_amsum[h] = ams;
    }
    __syncthreads();

    // ---- p[h][d] = sum_n am[h][n] * emb[n][h*64+d]  (reuse s_x) ----
    if (t < 256) {
        const int h = t >> 6, d = t & 63;
        float a = 0.0f;
        for (int n = 0; n < NOBJ; ++n)
            a += s_am[h * NOBJ + n] * s_h[n * EMB + h * HD + d];
        s_x[t] = a;
    }
    __syncthreads();

    // ---- out_emb[h][e] = sum_d p[h][d]*Wv[h][d][e] + amsum[h]*bv[h][e] ----
    if (t < 256) {
        const int h = t >> 6, e = t & 63;
        float a = s_amsum[h] * bv[h * HD + e];
        const float* w = &Wv[(size_t)h * HD * HD];
        for (int d = 0; d < HD; ++d)
            a += s_x[h * HD + d] * w[d * HD + e];
        out[(size_t)b * OUTC + EMB + t] = a;
    }
}

extern "C" void kernel_launch(void* const* d_in, const int* in_sizes, int n_in,
                              void* d_out, int out_size, void* d_ws, size_t ws_size,
                              hipStream_t stream)
{
    const float* obs = (const float*)d_in[0];
    const float* oW1 = (const float*)d_in[1];
    const float* ob1 = (const float*)d_in[2];
    const float* oW2 = (const float*)d_in[3];
    const float* ob2 = (const float*)d_in[4];
    const float* pW1 = (const float*)d_in[5];
    const float* pb1 = (const float*)d_in[6];
    const float* pW2 = (const float*)d_in[7];
    const float* pb2 = (const float*)d_in[8];
    const float* pW3 = (const float*)d_in[9];
    const float* pb3 = (const float*)d_in[10];
    const float* Wq  = (const float*)d_in[11];
    const float* bq  = (const float*)d_in[12];
    const float* Wk  = (const float*)d_in[13];
    const float* bk  = (const float*)d_in[14];
    const float* Wv  = (const float*)d_in[15];
    const float* bv  = (const float*)d_in[16];
    float* out = (float*)d_out;

    k_others<<<BATCH / 8, 256, 0, stream>>>(obs, oW1, ob1, oW2, ob2, out);
    k_objattn<<<BATCH, 512, 0, stream>>>(obs, pW1, pb1, pW2, pb2, pW3, pb3,
                                         Wq, bq, Wk, bk, Wv, bv, out);
}

// Round 2
// 565.988 us; speedup vs baseline: 2.8845x; 2.8845x over previous
//
#include <hip/hip_runtime.h>

#define BATCH      4096
#define OBS_COLS   2304
#define OTH_OFF    2048
#define NOBJ       64
#define EMB        256
#define NH         4
#define HD         64
#define OUTC       512

#define HSTR       264          // padded bf16 row stride for s_h (+8 kills bank conflicts)
#define Q_BYTES    (4096u * 256u * 4u)   // q buffer in ws, then packed weights

typedef __bf16 bf16x8 __attribute__((ext_vector_type(8)));
typedef float  f32x16 __attribute__((ext_vector_type(16)));

// ---------------------------------------------------------------------------
// k_prep: pack {pW1(zero-padded 31->32), pW2, pW3} as bf16 in MFMA B-fragment
// lane order. Slice s = one K-step (16 rows of W x 256 cols) = 4096 bf16 = 8KB.
// frag elem j of (ct,lane): W[kt*16 + (lane>>5)*8 + j][ct*32 + (lane&31)].
// ---------------------------------------------------------------------------
__global__ __launch_bounds__(512) void k_prep(
    const float* __restrict__ pW1, const float* __restrict__ pW2,
    const float* __restrict__ pW3, __bf16* __restrict__ wp)
{
    const int s = blockIdx.x;          // 0..33
    const int t = threadIdx.x;         // 0..511
    const int ct = t >> 6, lane = t & 63;
    int kt; const float* W; int isW1 = 0;
    if (s < 2)       { kt = s;      W = pW1; isW1 = 1; }
    else if (s < 18) { kt = s - 2;  W = pW2; }
    else             { kt = s - 18; W = pW3; }
    const int kbase = kt * 16 + (lane >> 5) * 8;
    const int n     = ct * 32 + (lane & 31);
    bf16x8 v;
    #pragma unroll
    for (int j = 0; j < 8; ++j) {
        const int k = kbase + j;
        const float f = (isW1 && k >= 31) ? 0.0f : W[k * 256 + n];
        v[j] = (__bf16)f;
    }
    ((bf16x8*)wp)[(size_t)s * 512 + t] = v;
}

// ---------------------------------------------------------------------------
// k_others: others_e (fp32 MLP, 8 rows/WG) -> d_out[:, 0:256], plus fused
// q = others_e @ Wq + bq -> ws q buffer.
// ---------------------------------------------------------------------------
__global__ __launch_bounds__(256, 2) void k_others(
    const float* __restrict__ obs,
    const float* __restrict__ oW1, const float* __restrict__ ob1,
    const float* __restrict__ oW2, const float* __restrict__ ob2,
    const float* __restrict__ Wq,  const float* __restrict__ bq,
    float* __restrict__ out, float* __restrict__ qout)
{
    __shared__ float s_in[8][256];
    __shared__ float s_t[8][256];
    const int j  = threadIdx.x;
    const int b0 = blockIdx.x * 8;

    #pragma unroll
    for (int r = 0; r < 8; ++r)
        s_in[r][j] = obs[(size_t)(b0 + r) * OBS_COLS + OTH_OFF + j];
    __syncthreads();

    float acc[8];
    {   // layer 1
        const float bias = ob1[j];
        #pragma unroll
        for (int r = 0; r < 8; ++r) acc[r] = bias;
        for (int i = 0; i < 256; i += 4) {
            const float w0 = oW1[(i + 0) * 256 + j];
            const float w1 = oW1[(i + 1) * 256 + j];
            const float w2 = oW1[(i + 2) * 256 + j];
            const float w3 = oW1[(i + 3) * 256 + j];
            #pragma unroll
            for (int r = 0; r < 8; ++r) {
                const float4 v = *(const float4*)&s_in[r][i];
                acc[r] += v.x * w0 + v.y * w1 + v.z * w2 + v.w * w3;
            }
        }
        #pragma unroll
        for (int r = 0; r < 8; ++r) s_t[r][j] = fmaxf(acc[r], 0.0f);
    }
    __syncthreads();
    {   // layer 2 (no relu)
        const float bias = ob2[j];
        #pragma unroll
        for (int r = 0; r < 8; ++r) acc[r] = bias;
        for (int i = 0; i < 256; i += 4) {
            const float w0 = oW2[(i + 0) * 256 + j];
            const float w1 = oW2[(i + 1) * 256 + j];
            const float w2 = oW2[(i + 2) * 256 + j];
            const float w3 = oW2[(i + 3) * 256 + j];
            #pragma unroll
            for (int r = 0; r < 8; ++r) {
                const float4 v = *(const float4*)&s_t[r][i];
                acc[r] += v.x * w0 + v.y * w1 + v.z * w2 + v.w * w3;
            }
        }
        #pragma unroll
        for (int r = 0; r < 8; ++r) {
            out[(size_t)(b0 + r) * OUTC + j] = acc[r];
            s_in[r][j] = acc[r];            // s_in reads finished at 1st barrier
        }
    }
    __syncthreads();
    {   // q = others_e @ Wq + bq
        const float bias = bq[j];
        #pragma unroll
        for (int r = 0; r < 8; ++r) acc[r] = bias;
        for (int i = 0; i < 256; i += 4) {
            const float w0 = Wq[(i + 0) * 256 + j];
            const float w1 = Wq[(i + 1) * 256 + j];
            const float w2 = Wq[(i + 2) * 256 + j];
            const float w3 = Wq[(i + 3) * 256 + j];
            #pragma unroll
            for (int r = 0; r < 8; ++r) {
                const float4 v = *(const float4*)&s_in[r][i];
                acc[r] += v.x * w0 + v.y * w1 + v.z * w2 + v.w * w3;
            }
        }
        #pragma unroll
        for (int r = 0; r < 8; ++r)
            qout[(size_t)(b0 + r) * 256 + j] = acc[r];
    }
}

// ---------------------------------------------------------------------------
// k_obj: one WG per 4 batch rows (M=256 object rows). bf16 MFMA object MLP
// (3 layers) with activations resident in LDS, then folded attention.
// Wave w: row-tiles {2(w&3), 2(w&3)+1}, col-tiles {4(w>>2)..+3}, 32x32x16.
// ---------------------------------------------------------------------------
__global__ __launch_bounds__(512, 2) void k_obj(
    const float* __restrict__ obs,  const __bf16* __restrict__ wp,
    const float* __restrict__ pb1,  const float* __restrict__ pb2,
    const float* __restrict__ pb3,  const float* __restrict__ qg,
    const float* __restrict__ bk,   const float* __restrict__ Wk,
    const float* __restrict__ bv,   const float* __restrict__ Wv,
    float* __restrict__ out)
{
    __shared__ __bf16 s_h[256 * HSTR];   // 135168 B: h1 -> h2 -> masked emb
    __shared__ __bf16 s_f[256 * 32];     // 16384 B: bf16 object feats (incl mask col)
    __shared__ float  s_mask[256];
    __shared__ float  s_qkp[16 * 64];    // qk, then p
    __shared__ float  s_am[16 * 64];     // attn*mask
    __shared__ float  s_amsum[16];

    const int t    = threadIdx.x;
    const int b0   = blockIdx.x * 4;
    const int wv   = t >> 6, lane = t & 63;
    const int lm   = lane & 31;          // m (A) / n (B) / col (C)
    const int lh   = lane >> 5;          // k-half selector
    const int rt0  = (wv & 3) * 2;
    const int ct0  = (wv >> 2) * 4;

    // ---- stage object feats as bf16 (mask col included; W1 row 31 is zero) ----
    {
        const int row = t >> 1, half = t & 1;
        const float* src = obs + (size_t)(b0 + (row >> 6)) * OBS_COLS
                               + (row & 63) * 32 + half * 16;
        __bf16* dst = s_f + row * 32 + half * 16;
        float vals[16];
        #pragma unroll
        for (int q4 = 0; q4 < 4; ++q4) {
            const float4 v = ((const float4*)src)[q4];
            vals[q4 * 4 + 0] = v.x; vals[q4 * 4 + 1] = v.y;
            vals[q4 * 4 + 2] = v.z; vals[q4 * 4 + 3] = v.w;
        }
        #pragma unroll
        for (int e = 0; e < 16; ++e) dst[e] = (__bf16)vals[e];
        if (half) s_mask[row] = vals[15];
    }
    __syncthreads();

    f32x16 acc[2][4];
    f32x16 vzero;
    #pragma unroll
    for (int i = 0; i < 16; ++i) vzero[i] = 0.0f;

    // ================= GEMM1: h1 = relu(feats @ W1p + b1), K=32 =================
    {
        const bf16x8* Bg = (const bf16x8*)wp;   // slices 0..1
        #pragma unroll
        for (int r = 0; r < 2; ++r)
            #pragma unroll
            for (int c = 0; c < 4; ++c) acc[r][c] = vzero;
        #pragma unroll
        for (int kt = 0; kt < 2; ++kt) {
            const bf16x8 a0 = *(const bf16x8*)&s_f[((rt0 + 0) * 32 + lm) * 32 + kt * 16 + lh * 8];
            const bf16x8 a1 = *(const bf16x8*)&s_f[((rt0 + 1) * 32 + lm) * 32 + kt * 16 + lh * 8];
            #pragma unroll
            for (int c = 0; c < 4; ++c) {
                const bf16x8 b = Bg[(kt * 8 + ct0 + c) * 64 + lane];
                acc[0][c] = __builtin_amdgcn_mfma_f32_32x32x16_bf16(a0, b, acc[0][c], 0, 0, 0);
                acc[1][c] = __builtin_amdgcn_mfma_f32_32x32x16_bf16(a1, b, acc[1][c], 0, 0, 0);
            }
        }
        // writeback (reads were from s_f; no hazard with s_h)
        #pragma unroll
        for (int r = 0; r < 2; ++r)
            #pragma unroll
            for (int c = 0; c < 4; ++c) {
                const int n = (ct0 + c) * 32 + lm;
                const float bias = pb1[n];
                #pragma unroll
                for (int g = 0; g < 4; ++g)
                    #pragma unroll
                    for (int q = 0; q < 4; ++q) {
                        const int row = (rt0 + r) * 32 + q + 8 * g + 4 * lh;
                        const float v = fmaxf(acc[r][c][g * 4 + q] + bias, 0.0f);
                        s_h[row * HSTR + n] = (__bf16)v;
                    }
            }
    }
    __syncthreads();

    // ================= GEMM2: h2 = relu(h1 @ W2 + b2), K=256 =================
    {
        const bf16x8* Bg = (const bf16x8*)wp + 2 * 512;
        #pragma unroll
        for (int r = 0; r < 2; ++r)
            #pragma unroll
            for (int c = 0; c < 4; ++c) acc[r][c] = vzero;
        for (int kt = 0; kt < 16; ++kt) {
            const bf16x8 a0 = *(const bf16x8*)&s_h[((rt0 + 0) * 32 + lm) * HSTR + kt * 16 + lh * 8];
            const bf16x8 a1 = *(const bf16x8*)&s_h[((rt0 + 1) * 32 + lm) * HSTR + kt * 16 + lh * 8];
            #pragma unroll
            for (int c = 0; c < 4; ++c) {
                const bf16x8 b = Bg[(kt * 8 + ct0 + c) * 64 + lane];
                acc[0][c] = __builtin_amdgcn_mfma_f32_32x32x16_bf16(a0, b, acc[0][c], 0, 0, 0);
                acc[1][c] = __builtin_amdgcn_mfma_f32_32x32x16_bf16(a1, b, acc[1][c], 0, 0, 0);
            }
        }
        __syncthreads();   // all reads of h1 complete before in-place overwrite
        #pragma unroll
        for (int r = 0; r < 2; ++r)
            #pragma unroll
            for (int c = 0; c < 4; ++c) {
                const int n = (ct0 + c) * 32 + lm;
                const float bias = pb2[n];
                #pragma unroll
                for (int g = 0; g < 4; ++g)
                    #pragma unroll
                    for (int q = 0; q < 4; ++q) {
                        const int row = (rt0 + r) * 32 + q + 8 * g + 4 * lh;
                        const float v = fmaxf(acc[r][c][g * 4 + q] + bias, 0.0f);
                        s_h[row * HSTR + n] = (__bf16)v;
                    }
            }
    }
    __syncthreads();

    // ============ GEMM3: E = (h2 @ W3 + b3) * mask, K=256 (no relu) ============
    {
        const bf16x8* Bg = (const bf16x8*)wp + 18 * 512;
        #pragma unroll
        for (int r = 0; r < 2; ++r)
            #pragma unroll
            for (int c = 0; c < 4; ++c) acc[r][c] = vzero;
        for (int kt = 0; kt < 16; ++kt) {
            const bf16x8 a0 = *(const bf16x8*)&s_h[((rt0 + 0) * 32 + lm) * HSTR + kt * 16 + lh * 8];
            const bf16x8 a1 = *(const bf16x8*)&s_h[((rt0 + 1) * 32 + lm) * HSTR + kt * 16 + lh * 8];
            #pragma unroll
            for (int c = 0; c < 4; ++c) {
                const bf16x8 b = Bg[(kt * 8 + ct0 + c) * 64 + lane];
                acc[0][c] = __builtin_amdgcn_mfma_f32_32x32x16_bf16(a0, b, acc[0][c], 0, 0, 0);
                acc[1][c] = __builtin_amdgcn_mfma_f32_32x32x16_bf16(a1, b, acc[1][c], 0, 0, 0);
            }
        }
        __syncthreads();
        #pragma unroll
        for (int r = 0; r < 2; ++r)
            #pragma unroll
            for (int c = 0; c < 4; ++c) {
                const int n = (ct0 + c) * 32 + lm;
                const float bias = pb3[n];
                #pragma unroll
                for (int g = 0; g < 4; ++g)
                    #pragma unroll
                    for (int q = 0; q < 4; ++q) {
                        const int row = (rt0 + r) * 32 + q + 8 * g + 4 * lh;
                        const float v = (acc[r][c][g * 4 + q] + bias) * s_mask[row];
                        s_h[row * HSTR + n] = (__bf16)v;
                    }
            }
    }
    __syncthreads();

    // ================= attention (folded Wk / Wv), 4 rows x 4 heads =================
    // Phase A: qk[r][h][d] = sum_e Wk[h][d][e] * q[r][h][e]
    #pragma unroll
    for (int i = 0; i < 2; ++i) {
        const int idx = i * 512 + t;
        const int r = idx >> 8, h = (idx >> 6) & 3, d = idx & 63;
        const float* wkr = Wk + ((size_t)h * 64 + d) * 64;
        const float* q_r = qg + (size_t)(b0 + r) * 256 + h * 64;
        float a = 0.0f;
        for (int e = 0; e < 64; e += 4) {
            const float4 w = *(const float4*)&wkr[e];
            const float4 q = *(const float4*)&q_r[e];
            a += w.x * q.x + w.y * q.y + w.z * q.z + w.w * q.w;
        }
        s_qkp[(r * 4 + h) * 64 + d] = a;
    }
    __syncthreads();

    // Phase B: logits + softmax (wave handles 2 (row,head) units; lane = object)
    #pragma unroll
    for (int i = 0; i < 2; ++i) {
        const int u = wv * 2 + i;
        const int r = u >> 2, h = u & 3;
        const float* q_r = qg + (size_t)(b0 + r) * 256 + h * 64;
        float qb = q_r[lane] * bk[h * 64 + lane];
        #pragma unroll
        for (int off = 32; off > 0; off >>= 1) qb += __shfl_xor(qb, off, 64);
        float dot = 0.0f;
        #pragma unroll
        for (int d8 = 0; d8 < 8; ++d8) {
            const bf16x8 ev = *(const bf16x8*)&s_h[(r * 64 + lane) * HSTR + h * 64 + d8 * 8];
            const float* kv = &s_qkp[(r * 4 + h) * 64 + d8 * 8];
            #pragma unroll
            for (int j = 0; j < 8; ++j) dot += (float)ev[j] * kv[j];
        }
        const float mk = s_mask[r * 64 + lane];
        float logit = (dot + qb) * 0.0625f;
        if (mk == 0.0f) logit = -1.0e9f;
        float m = logit;
        #pragma unroll
        for (int off = 32; off > 0; off >>= 1) m = fmaxf(m, __shfl_xor(m, off, 64));
        const float ex = __expf(logit - m);
        float ssum = ex;
        #pragma unroll
        for (int off = 32; off > 0; off >>= 1) ssum += __shfl_xor(ssum, off, 64);
        const float am = (ex / ssum) * mk;
        s_am[(r * 4 + h) * 64 + lane] = am;
        float ams = am;
        #pragma unroll
        for (int off = 32; off > 0; off >>= 1) ams += __shfl_xor(ams, off, 64);
        if (lane == 0) s_amsum[r * 4 + h] = ams;
    }
    __syncthreads();

    // Phase C: p[r][h][d] = sum_n am * E[n][h*64+d]   (reuse s_qkp)
    #pragma unroll
    for (int i = 0; i < 2; ++i) {
        const int idx = i * 512 + t;
        const int r = idx >> 8, h = (idx >> 6) & 3, d = idx & 63;
        const float* amr = &s_am[(r * 4 + h) * 64];
        float a = 0.0f;
        for (int n = 0; n < 64; ++n)
            a += amr[n] * (float)s_h[(r * 64 + n) * HSTR + h * 64 + d];
        __syncthreads();   // ensure Phase-B readers of s_qkp are done before overwrite
        s_qkp[(r * 4 + h) * 64 + d] = a;
        __syncthreads();
    }

    // Phase D: out_emb[r][h][e] = sum_d p*Wv[h][d][e] + amsum*bv
    #pragma unroll
    for (int i = 0; i < 2; ++i) {
        const int idx = i * 512 + t;
        const int r = idx >> 8, h = (idx >> 6) & 3, e = idx & 63;
        float a = s_amsum[r * 4 + h] * bv[h * 64 + e];
        const float* pr  = &s_qkp[(r * 4 + h) * 64];
        const float* wvp = Wv + (size_t)h * 64 * 64;
        for (int d = 0; d < 64; ++d)
            a += pr[d] * wvp[d * 64 + e];
        out[(size_t)(b0 + r) * OUTC + EMB + h * 64 + e] = a;
    }
}

extern "C" void kernel_launch(void* const* d_in, const int* in_sizes, int n_in,
                              void* d_out, int out_size, void* d_ws, size_t ws_size,
                              hipStream_t stream)
{
    const float* obs = (const float*)d_in[0];
    const float* oW1 = (const float*)d_in[1];
    const float* ob1 = (const float*)d_in[2];
    const float* oW2 = (const float*)d_in[3];
    const float* ob2 = (const float*)d_in[4];
    const float* pW1 = (const float*)d_in[5];
    const float* pb1 = (const float*)d_in[6];
    const float* pW2 = (const float*)d_in[7];
    const float* pb2 = (const float*)d_in[8];
    const float* pW3 = (const float*)d_in[9];
    const float* pb3 = (const float*)d_in[10];
    const float* Wq  = (const float*)d_in[11];
    const float* bq  = (const float*)d_in[12];
    const float* Wk  = (const float*)d_in[13];
    const float* bk  = (const float*)d_in[14];
    const float* Wv  = (const float*)d_in[15];
    const float* bv  = (const float*)d_in[16];
    float*  out = (float*)d_out;
    float*  qg  = (float*)d_ws;
    __bf16* wp  = (__bf16*)((char*)d_ws + Q_BYTES);

    k_prep<<<34, 512, 0, stream>>>(pW1, pW2, pW3, wp);
    k_others<<<BATCH / 8, 256, 0, stream>>>(obs, oW1, ob1, oW2, ob2, Wq, bq, out, qg);
    k_obj<<<BATCH / 4, 512, 0, stream>>>(obs, wp, pb1, pb2, pb3, qg,
                                         bk, Wk, bv, Wv, out);
}

// Round 3
// 326.809 us; speedup vs baseline: 4.9955x; 1.7319x over previous
//
#include <hip/hip_runtime.h>

#define BATCH      4096
#define OBS_COLS   2304
#define OTH_OFF    2048
#define EMB        256
#define OUTC       512
#define HSTR       264
#define Q_BYTES    (4096u * 256u * 4u)

typedef __bf16 bf16x8 __attribute__((ext_vector_type(8)));
typedef __bf16 bf16x4 __attribute__((ext_vector_type(4)));
typedef float  f32x16 __attribute__((ext_vector_type(16)));

// Slice bases (units of 512 bf16x8 = one 16x256 K-step slice)
#define S_PW1  0
#define S_PW2  2
#define S_PW3  18
#define S_OW1  34
#define S_OW2  50
#define S_WQ   66

// ---------------------------------------------------------------------------
// k_prep: pack 6 weight matrices as bf16 MFMA B-fragments.
// frag elem j of (ct,lane): W[kt*16 + (lane>>5)*8 + j][ct*32 + (lane&31)].
// ---------------------------------------------------------------------------
__global__ __launch_bounds__(512) void k_prep(
    const float* __restrict__ pW1, const float* __restrict__ pW2,
    const float* __restrict__ pW3, const float* __restrict__ oW1,
    const float* __restrict__ oW2, const float* __restrict__ Wq,
    __bf16* __restrict__ wp)
{
    const int s = blockIdx.x;          // 0..81
    const int t = threadIdx.x;
    const int ct = t >> 6, lane = t & 63;
    int kt; const float* W; int isW1 = 0;
    if      (s < S_PW2) { kt = s;         W = pW1; isW1 = 1; }
    else if (s < S_PW3) { kt = s - S_PW2; W = pW2; }
    else if (s < S_OW1) { kt = s - S_PW3; W = pW3; }
    else if (s < S_OW2) { kt = s - S_OW1; W = oW1; }
    else if (s < S_WQ)  { kt = s - S_OW2; W = oW2; }
    else                { kt = s - S_WQ;  W = Wq; }
    const int kbase = kt * 16 + (lane >> 5) * 8;
    const int n     = ct * 32 + (lane & 31);
    bf16x8 v;
    #pragma unroll
    for (int j = 0; j < 8; ++j) {
        const int k = kbase + j;
        const float f = (isW1 && k >= 31) ? 0.0f : W[k * 256 + n];
        v[j] = (__bf16)f;
    }
    ((bf16x8*)wp)[(size_t)s * 512 + t] = v;
}

// ---------------------------------------------------------------------------
// k_oth: others MLP via MFMA. M=64 rows/WG, 256 thr (4 waves), 64 WGs.
// L1: relu(A@oW1+b1) -> s_h ; L2: s_h@oW2+b2 -> out[:, :256] + s_a(bf16)
// L3: s_a@Wq+bq -> qg.  Wave w: rt=w&1, ct0=(w>>1)*4, acc 1x4 tiles.
// Transposed mfma(b,a): lane holds row=lm, 4 consecutive cols per reg-group.
// ---------------------------------------------------------------------------
__global__ __launch_bounds__(256, 2) void k_oth(
    const float* __restrict__ obs, const __bf16* __restrict__ wp,
    const float* __restrict__ ob1, const float* __restrict__ ob2,
    const float* __restrict__ bq,
    float* __restrict__ out, float* __restrict__ qg)
{
    __shared__ __bf16 s_a[64 * HSTR];   // 33792 B
    __shared__ __bf16 s_h[64 * HSTR];   // 33792 B

    const int t  = threadIdx.x;
    const int b0 = blockIdx.x * 64;
    const int wv = t >> 6, lane = t & 63;
    const int lm = lane & 31, lh = lane >> 5;
    const int rt  = wv & 1;
    const int ct0 = (wv >> 1) * 4;

    // stage others (64 rows x 256 cols fp32 -> bf16)
    {
        const int row = t >> 2, q4 = t & 3;
        const float* src = obs + (size_t)(b0 + row) * OBS_COLS + OTH_OFF + q4 * 64;
        __bf16* dst = s_a + row * HSTR + q4 * 64;
        #pragma unroll
        for (int c8 = 0; c8 < 8; ++c8) {
            const float4 v0 = ((const float4*)src)[c8 * 2 + 0];
            const float4 v1 = ((const float4*)src)[c8 * 2 + 1];
            bf16x8 o;
            o[0]=(__bf16)v0.x; o[1]=(__bf16)v0.y; o[2]=(__bf16)v0.z; o[3]=(__bf16)v0.w;
            o[4]=(__bf16)v1.x; o[5]=(__bf16)v1.y; o[6]=(__bf16)v1.z; o[7]=(__bf16)v1.w;
            *(bf16x8*)&dst[c8 * 8] = o;
        }
    }
    __syncthreads();

    f32x16 acc[4];
    f32x16 vzero;
    #pragma unroll
    for (int i = 0; i < 16; ++i) vzero[i] = 0.0f;

    // ---- L1: h = relu(A @ oW1 + ob1) ----
    {
        const bf16x8* Bg = (const bf16x8*)wp + S_OW1 * 512;
        #pragma unroll
        for (int c = 0; c < 4; ++c) acc[c] = vzero;
        #pragma unroll 2
        for (int kt = 0; kt < 16; ++kt) {
            const bf16x8 a = *(const bf16x8*)&s_a[(rt * 32 + lm) * HSTR + kt * 16 + lh * 8];
            #pragma unroll
            for (int c = 0; c < 4; ++c) {
                const bf16x8 b = Bg[(kt * 8 + ct0 + c) * 64 + lane];
                acc[c] = __builtin_amdgcn_mfma_f32_32x32x16_bf16(b, a, acc[c], 0, 0, 0);
            }
        }
        #pragma unroll
        for (int c = 0; c < 4; ++c) {
            __bf16* dst = &s_h[(rt * 32 + lm) * HSTR + (ct0 + c) * 32 + 4 * lh];
            const float* bias = &ob1[(ct0 + c) * 32 + 4 * lh];
            #pragma unroll
            for (int g = 0; g < 4; ++g) {
                bf16x4 v;
                #pragma unroll
                for (int q = 0; q < 4; ++q)
                    v[q] = (__bf16)fmaxf(acc[c][g * 4 + q] + bias[8 * g + q], 0.0f);
                *(bf16x4*)&dst[8 * g] = v;
            }
        }
    }
    __syncthreads();

    // ---- L2: e = s_h @ oW2 + ob2 (no relu) -> out + s_a ----
    {
        const bf16x8* Bg = (const bf16x8*)wp + S_OW2 * 512;
        #pragma unroll
        for (int c = 0; c < 4; ++c) acc[c] = vzero;
        #pragma unroll 2
        for (int kt = 0; kt < 16; ++kt) {
            const bf16x8 a = *(const bf16x8*)&s_h[(rt * 32 + lm) * HSTR + kt * 16 + lh * 8];
            #pragma unroll
            for (int c = 0; c < 4; ++c) {
                const bf16x8 b = Bg[(kt * 8 + ct0 + c) * 64 + lane];
                acc[c] = __builtin_amdgcn_mfma_f32_32x32x16_bf16(b, a, acc[c], 0, 0, 0);
            }
        }
        const int row = rt * 32 + lm;
        #pragma unroll
        for (int c = 0; c < 4; ++c) {
            const float* bias = &ob2[(ct0 + c) * 32 + 4 * lh];
            __bf16* dstl = &s_a[row * HSTR + (ct0 + c) * 32 + 4 * lh];
            float*  dstg = &out[(size_t)(b0 + row) * OUTC + (ct0 + c) * 32 + 4 * lh];
            #pragma unroll
            for (int g = 0; g < 4; ++g) {
                float4 fv;
                bf16x4 v;
                float* fp = &fv.x;
                #pragma unroll
                for (int q = 0; q < 4; ++q) {
                    const float f = acc[c][g * 4 + q] + bias[8 * g + q];
                    fp[q] = f;
                    v[q] = (__bf16)f;
                }
                *(float4*)&dstg[8 * g] = fv;
                *(bf16x4*)&dstl[8 * g] = v;
            }
        }
    }
    __syncthreads();

    // ---- L3: q = s_a @ Wq + bq -> qg ----
    {
        const bf16x8* Bg = (const bf16x8*)wp + S_WQ * 512;
        #pragma unroll
        for (int c = 0; c < 4; ++c) acc[c] = vzero;
        #pragma unroll 2
        for (int kt = 0; kt < 16; ++kt) {
            const bf16x8 a = *(const bf16x8*)&s_a[(rt * 32 + lm) * HSTR + kt * 16 + lh * 8];
            #pragma unroll
            for (int c = 0; c < 4; ++c) {
                const bf16x8 b = Bg[(kt * 8 + ct0 + c) * 64 + lane];
                acc[c] = __builtin_amdgcn_mfma_f32_32x32x16_bf16(b, a, acc[c], 0, 0, 0);
            }
        }
        const int row = rt * 32 + lm;
        #pragma unroll
        for (int c = 0; c < 4; ++c) {
            const float* bias = &bq[(ct0 + c) * 32 + 4 * lh];
            float* dstg = &qg[(size_t)(b0 + row) * 256 + (ct0 + c) * 32 + 4 * lh];
            #pragma unroll
            for (int g = 0; g < 4; ++g) {
                float4 fv;
                float* fp = &fv.x;
                #pragma unroll
                for (int q = 0; q < 4; ++q)
                    fp[q] = acc[c][g * 4 + q] + bias[8 * g + q];
                *(float4*)&dstg[8 * g] = fv;
            }
        }
    }
}

// ---------------------------------------------------------------------------
// k_obj: M=128 (2 batch rows)/WG, 256 thr (4 waves), 2048 WGs, ~80KB LDS
// -> 2 WGs/CU. Wave w: rt0=(w&1)*2, ct0=(w>>1)*4, acc 2x4 tiles (128 regs).
// ---------------------------------------------------------------------------
__global__ __launch_bounds__(256, 2) void k_obj(
    const float* __restrict__ obs,  const __bf16* __restrict__ wp,
    const float* __restrict__ pb1,  const float* __restrict__ pb2,
    const float* __restrict__ pb3,  const float* __restrict__ qg,
    const float* __restrict__ bk,   const float* __restrict__ Wk,
    const float* __restrict__ bv,   const float* __restrict__ Wv,
    float* __restrict__ out)
{
    __shared__ __bf16 s_h[128 * HSTR];          // 67584 B
    __shared__ __align__(16) char s_fp[8192];   // feats, later p
    __bf16* s_f = (__bf16*)s_fp;
    float*  s_p = (float*)s_fp;
    __shared__ float s_mask[128];
    __shared__ float s_qk[8 * 64];
    __shared__ float s_am[8 * 64];
    __shared__ float s_amsum[8];

    const int t  = threadIdx.x;
    const int b0 = blockIdx.x * 2;
    const int wv = t >> 6, lane = t & 63;
    const int lm = lane & 31, lh = lane >> 5;
    const int rt0 = (wv & 1) * 2;
    const int ct0 = (wv >> 1) * 4;

    // stage 128 object rows (64/batch-row) of 32 feats as bf16 + mask col
    {
        const int row = t >> 1, half = t & 1;
        const float* src = obs + (size_t)(b0 + (row >> 6)) * OBS_COLS
                               + (row & 63) * 32 + half * 16;
        __bf16* dst = s_f + row * 32 + half * 16;
        float last = 0.0f;
        #pragma unroll
        for (int q4 = 0; q4 < 4; ++q4) {
            const float4 v = ((const float4*)src)[q4];
            bf16x4 o;
            o[0]=(__bf16)v.x; o[1]=(__bf16)v.y; o[2]=(__bf16)v.z; o[3]=(__bf16)v.w;
            *(bf16x4*)&dst[q4 * 4] = o;
            last = v.w;
        }
        if (half) s_mask[row] = last;
    }
    __syncthreads();

    f32x16 acc[2][4];
    f32x16 vzero;
    #pragma unroll
    for (int i = 0; i < 16; ++i) vzero[i] = 0.0f;

    // ========== GEMM1: h1 = relu(feats @ W1p + b1), K=32 ==========
    {
        const bf16x8* Bg = (const bf16x8*)wp + S_PW1 * 512;
        #pragma unroll
        for (int r = 0; r < 2; ++r)
            #pragma unroll
            for (int c = 0; c < 4; ++c) acc[r][c] = vzero;
        #pragma unroll
        for (int kt = 0; kt < 2; ++kt) {
            const bf16x8 a0 = *(const bf16x8*)&s_f[((rt0 + 0) * 32 + lm) * 32 + kt * 16 + lh * 8];
            const bf16x8 a1 = *(const bf16x8*)&s_f[((rt0 + 1) * 32 + lm) * 32 + kt * 16 + lh * 8];
            #pragma unroll
            for (int c = 0; c < 4; ++c) {
                const bf16x8 b = Bg[(kt * 8 + ct0 + c) * 64 + lane];
                acc[0][c] = __builtin_amdgcn_mfma_f32_32x32x16_bf16(b, a0, acc[0][c], 0, 0, 0);
                acc[1][c] = __builtin_amdgcn_mfma_f32_32x32x16_bf16(b, a1, acc[1][c], 0, 0, 0);
            }
        }
        #pragma unroll
        for (int r = 0; r < 2; ++r)
            #pragma unroll
            for (int c = 0; c < 4; ++c) {
                __bf16* dst = &s_h[((rt0 + r) * 32 + lm) * HSTR + (ct0 + c) * 32 + 4 * lh];
                const float* bias = &pb1[(ct0 + c) * 32 + 4 * lh];
                #pragma unroll
                for (int g = 0; g < 4; ++g) {
                    bf16x4 v;
                    #pragma unroll
                    for (int q = 0; q < 4; ++q)
                        v[q] = (__bf16)fmaxf(acc[r][c][g * 4 + q] + bias[8 * g + q], 0.0f);
                    *(bf16x4*)&dst[8 * g] = v;
                }
            }
    }
    __syncthreads();

    // ========== GEMM2: h2 = relu(h1 @ W2 + b2), K=256 ==========
    {
        const bf16x8* Bg = (const bf16x8*)wp + S_PW2 * 512;
        #pragma unroll
        for (int r = 0; r < 2; ++r)
            #pragma unroll
            for (int c = 0; c < 4; ++c) acc[r][c] = vzero;
        #pragma unroll 2
        for (int kt = 0; kt < 16; ++kt) {
            const bf16x8 a0 = *(const bf16x8*)&s_h[((rt0 + 0) * 32 + lm) * HSTR + kt * 16 + lh * 8];
            const bf16x8 a1 = *(const bf16x8*)&s_h[((rt0 + 1) * 32 + lm) * HSTR + kt * 16 + lh * 8];
            #pragma unroll
            for (int c = 0; c < 4; ++c) {
                const bf16x8 b = Bg[(kt * 8 + ct0 + c) * 64 + lane];
                acc[0][c] = __builtin_amdgcn_mfma_f32_32x32x16_bf16(b, a0, acc[0][c], 0, 0, 0);
                acc[1][c] = __builtin_amdgcn_mfma_f32_32x32x16_bf16(b, a1, acc[1][c], 0, 0, 0);
            }
        }
        __syncthreads();
        #pragma unroll
        for (int r = 0; r < 2; ++r)
            #pragma unroll
            for (int c = 0; c < 4; ++c) {
                __bf16* dst = &s_h[((rt0 + r) * 32 + lm) * HSTR + (ct0 + c) * 32 + 4 * lh];
                const float* bias = &pb2[(ct0 + c) * 32 + 4 * lh];
                #pragma unroll
                for (int g = 0; g < 4; ++g) {
                    bf16x4 v;
                    #pragma unroll
                    for (int q = 0; q < 4; ++q)
                        v[q] = (__bf16)fmaxf(acc[r][c][g * 4 + q] + bias[8 * g + q], 0.0f);
                    *(bf16x4*)&dst[8 * g] = v;
                }
            }
    }
    __syncthreads();

    // ========== GEMM3: E = (h2 @ W3 + b3) * mask, K=256 ==========
    {
        const bf16x8* Bg = (const bf16x8*)wp + S_PW3 * 512;
        #pragma unroll
        for (int r = 0; r < 2; ++r)
            #pragma unroll
            for (int c = 0; c < 4; ++c) acc[r][c] = vzero;
        #pragma unroll 2
        for (int kt = 0; kt < 16; ++kt) {
            const bf16x8 a0 = *(const bf16x8*)&s_h[((rt0 + 0) * 32 + lm) * HSTR + kt * 16 + lh * 8];
            const bf16x8 a1 = *(const bf16x8*)&s_h[((rt0 + 1) * 32 + lm) * HSTR + kt * 16 + lh * 8];
            #pragma unroll
            for (int c = 0; c < 4; ++c) {
                const bf16x8 b = Bg[(kt * 8 + ct0 + c) * 64 + lane];
                acc[0][c] = __builtin_amdgcn_mfma_f32_32x32x16_bf16(b, a0, acc[0][c], 0, 0, 0);
                acc[1][c] = __builtin_amdgcn_mfma_f32_32x32x16_bf16(b, a1, acc[1][c], 0, 0, 0);
            }
        }
        __syncthreads();
        #pragma unroll
        for (int r = 0; r < 2; ++r) {
            const float mk = s_mask[(rt0 + r) * 32 + lm];
            #pragma unroll
            for (int c = 0; c < 4; ++c) {
                __bf16* dst = &s_h[((rt0 + r) * 32 + lm) * HSTR + (ct0 + c) * 32 + 4 * lh];
                const float* bias = &pb3[(ct0 + c) * 32 + 4 * lh];
                #pragma unroll
                for (int g = 0; g < 4; ++g) {
                    bf16x4 v;
                    #pragma unroll
                    for (int q = 0; q < 4; ++q)
                        v[q] = (__bf16)((acc[r][c][g * 4 + q] + bias[8 * g + q]) * mk);
                    *(bf16x4*)&dst[8 * g] = v;
                }
            }
        }
    }
    __syncthreads();

    // ---- Phase A: qk[r][h][d] = sum_e Wk[h][d][e] * q[r][h][e] ----
    #pragma unroll
    for (int i = 0; i < 2; ++i) {
        const int idx = i * 256 + t;
        const int r = idx >> 8, h = (idx >> 6) & 3, d = idx & 63;
        const float* wkr = Wk + ((size_t)h * 64 + d) * 64;
        const float* q_r = qg + (size_t)(b0 + r) * 256 + h * 64;
        float a = 0.0f;
        for (int e = 0; e < 64; e += 4) {
            const float4 w = *(const float4*)&wkr[e];
            const float4 q = *(const float4*)&q_r[e];
            a += w.x * q.x + w.y * q.y + w.z * q.z + w.w * q.w;
        }
        s_qk[(r * 4 + h) * 64 + d] = a;
    }
    __syncthreads();

    // ---- Phase B: logits + softmax (wave: 2 (r,h) units; lane = object) ----
    #pragma unroll
    for (int i = 0; i < 2; ++i) {
        const int u = wv * 2 + i;
        const int r = u >> 2, h = u & 3;
        const float* q_r = qg + (size_t)(b0 + r) * 256 + h * 64;
        float qb = q_r[lane] * bk[h * 64 + lane];
        #pragma unroll
        for (int off = 32; off > 0; off >>= 1) qb += __shfl_xor(qb, off, 64);
        float dot = 0.0f;
        #pragma unroll
        for (int d8 = 0; d8 < 8; ++d8) {
            const bf16x8 ev = *(const bf16x8*)&s_h[(r * 64 + lane) * HSTR + h * 64 + d8 * 8];
            const float* kv = &s_qk[(r * 4 + h) * 64 + d8 * 8];
            #pragma unroll
            for (int j = 0; j < 8; ++j) dot += (float)ev[j] * kv[j];
        }
        const float mk = s_mask[r * 64 + lane];
        float logit = (dot + qb) * 0.0625f;
        if (mk == 0.0f) logit = -1.0e9f;
        float m = logit;
        #pragma unroll
        for (int off = 32; off > 0; off >>= 1) m = fmaxf(m, __shfl_xor(m, off, 64));
        const float ex = __expf(logit - m);
        float ssum = ex;
        #pragma unroll
        for (int off = 32; off > 0; off >>= 1) ssum += __shfl_xor(ssum, off, 64);
        const float am = (ex / ssum) * mk;
        s_am[(r * 4 + h) * 64 + lane] = am;
        float ams = am;
        #pragma unroll
        for (int off = 32; off > 0; off >>= 1) ams += __shfl_xor(ams, off, 64);
        if (lane == 0) s_amsum[r * 4 + h] = ams;
    }
    __syncthreads();

    // ---- Phase C: p[r][h][d] = sum_n am * E[n][h*64+d] -> s_p (old s_f) ----
    #pragma unroll
    for (int i = 0; i < 2; ++i) {
        const int idx = i * 256 + t;
        const int r = idx >> 8, h = (idx >> 6) & 3, d = idx & 63;
        const float* amr = &s_am[(r * 4 + h) * 64];
        float a = 0.0f;
        for (int n = 0; n < 64; ++n)
            a += amr[n] * (float)s_h[(r * 64 + n) * HSTR + h * 64 + d];
        s_p[(r * 4 + h) * 64 + d] = a;
    }
    __syncthreads();

    // ---- Phase D: out_emb = p @ Wv + amsum * bv ----
    #pragma unroll
    for (int i = 0; i < 2; ++i) {
        const int idx = i * 256 + t;
        const int r = idx >> 8, h = (idx >> 6) & 3, e = idx & 63;
        float a = s_amsum[r * 4 + h] * bv[h * 64 + e];
        const float* pr  = &s_p[(r * 4 + h) * 64];
        const float* wvp = Wv + (size_t)h * 64 * 64;
        for (int d = 0; d < 64; ++d)
            a += pr[d] * wvp[d * 64 + e];
        out[(size_t)(b0 + r) * OUTC + EMB + h * 64 + e] = a;
    }
}

extern "C" void kernel_launch(void* const* d_in, const int* in_sizes, int n_in,
                              void* d_out, int out_size, void* d_ws, size_t ws_size,
                              hipStream_t stream)
{
    const float* obs = (const float*)d_in[0];
    const float* oW1 = (const float*)d_in[1];
    const float* ob1 = (const float*)d_in[2];
    const float* oW2 = (const float*)d_in[3];
    const float* ob2 = (const float*)d_in[4];
    const float* pW1 = (const float*)d_in[5];
    const float* pb1 = (const float*)d_in[6];
    const float* pW2 = (const float*)d_in[7];
    const float* pb2 = (const float*)d_in[8];
    const float* pW3 = (const float*)d_in[9];
    const float* pb3 = (const float*)d_in[10];
    const float* Wq  = (const float*)d_in[11];
    const float* bq  = (const float*)d_in[12];
    const float* Wk  = (const float*)d_in[13];
    const float* bk  = (const float*)d_in[14];
    const float* Wv  = (const float*)d_in[15];
    const float* bv  = (const float*)d_in[16];
    float*  out = (float*)d_out;
    float*  qg  = (float*)d_ws;
    __bf16* wp  = (__bf16*)((char*)d_ws + Q_BYTES);

    k_prep<<<82, 512, 0, stream>>>(pW1, pW2, pW3, oW1, oW2, Wq, wp);
    k_oth<<<BATCH / 64, 256, 0, stream>>>(obs, wp, ob1, ob2, bq, out, qg);
    k_obj<<<BATCH / 2, 256, 0, stream>>>(obs, wp, pb1, pb2, pb3, qg,
                                         bk, Wk, bv, Wv, out);
}

// Round 4
// 287.895 us; speedup vs baseline: 5.6707x; 1.1352x over previous
//
#include <hip/hip_runtime.h>

#define BATCH      4096
#define OBS_COLS   2304
#define OTH_OFF    2048
#define EMB        256
#define OUTC       512
#define Q_BYTES    (4096u * 256u * 4u)

typedef __bf16 bf16x8 __attribute__((ext_vector_type(8)));
typedef __bf16 bf16x4 __attribute__((ext_vector_type(4)));
typedef float  f32x16 __attribute__((ext_vector_type(16)));

// Slice bases (units of 512 bf16x8 = one 16x256 K-step slice)
#define S_PW1  0
#define S_PW2  2
#define S_PW3  18
#define S_OW1  34
#define S_OW2  50
#define S_WQ   66

// Swizzled element index into a [rows][256] bf16 LDS tile:
// 16-B blocks within a row are XORed with (row & 31) -> conflict-free
// ds_read_b128 / ds_write_b64 for the MFMA access patterns.
__device__ __forceinline__ int shx(int row, int col) {
    return (row << 8) + ((((col >> 3) ^ (row & 31)) << 3) | (col & 7));
}

// ---------------------------------------------------------------------------
// k_prep: pack 6 weight matrices as bf16 MFMA B-fragments.
// frag elem j of (ct,lane): W[kt*16 + (lane>>5)*8 + j][ct*32 + (lane&31)].
// ---------------------------------------------------------------------------
__global__ __launch_bounds__(512) void k_prep(
    const float* __restrict__ pW1, const float* __restrict__ pW2,
    const float* __restrict__ pW3, const float* __restrict__ oW1,
    const float* __restrict__ oW2, const float* __restrict__ Wq,
    __bf16* __restrict__ wp)
{
    const int s = blockIdx.x;          // 0..81
    const int t = threadIdx.x;
    const int ct = t >> 6, lane = t & 63;
    int kt; const float* W; int isW1 = 0;
    if      (s < S_PW2) { kt = s;         W = pW1; isW1 = 1; }
    else if (s < S_PW3) { kt = s - S_PW2; W = pW2; }
    else if (s < S_OW1) { kt = s - S_PW3; W = pW3; }
    else if (s < S_OW2) { kt = s - S_OW1; W = oW1; }
    else if (s < S_WQ)  { kt = s - S_OW2; W = oW2; }
    else                { kt = s - S_WQ;  W = Wq; }
    const int kbase = kt * 16 + (lane >> 5) * 8;
    const int n     = ct * 32 + (lane & 31);
    bf16x8 v;
    #pragma unroll
    for (int j = 0; j < 8; ++j) {
        const int k = kbase + j;
        const float f = (isW1 && k >= 31) ? 0.0f : W[k * 256 + n];
        v[j] = (__bf16)f;
    }
    ((bf16x8*)wp)[(size_t)s * 512 + t] = v;
}

// ---------------------------------------------------------------------------
// k_oth: others MLP via MFMA. M=32 rows/WG, 256 thr (4 waves), 128 WGs.
// Wave wv: ct0 = wv*2 (tile 32x64). Depth-1 rotation on B (L2) + A (LDS).
// L1: relu(A@oW1+b1)->s_h ; L2: s_h@oW2+b2 -> out + s_a ; L3: s_a@Wq+bq -> qg
// ---------------------------------------------------------------------------
__global__ __launch_bounds__(256, 2) void k_oth(
    const float* __restrict__ obs, const __bf16* __restrict__ wp,
    const float* __restrict__ ob1, const float* __restrict__ ob2,
    const float* __restrict__ bq,
    float* __restrict__ out, float* __restrict__ qg)
{
    __shared__ __align__(16) __bf16 s_a[32 * 256];   // 16 KB
    __shared__ __align__(16) __bf16 s_h[32 * 256];   // 16 KB

    const int t  = threadIdx.x;
    const int b0 = blockIdx.x * 32;
    const int wv = t >> 6, lane = t & 63;
    const int lm = lane & 31, lh = lane >> 5;
    const int ct0 = wv * 2;

    // stage 32 rows x 256 cols (fp32 -> bf16, swizzled)
    {
        const int row = t >> 3, seg = t & 7;
        const float* src = obs + (size_t)(b0 + row) * OBS_COLS + OTH_OFF + seg * 32;
        #pragma unroll
        for (int j = 0; j < 4; ++j) {
            const float4 v0 = ((const float4*)src)[j * 2 + 0];
            const float4 v1 = ((const float4*)src)[j * 2 + 1];
            bf16x8 o;
            o[0]=(__bf16)v0.x; o[1]=(__bf16)v0.y; o[2]=(__bf16)v0.z; o[3]=(__bf16)v0.w;
            o[4]=(__bf16)v1.x; o[5]=(__bf16)v1.y; o[6]=(__bf16)v1.z; o[7]=(__bf16)v1.w;
            *(bf16x8*)&s_a[shx(row, seg * 32 + j * 8)] = o;
        }
    }
    __syncthreads();

    f32x16 acc[2];
    f32x16 vzero;
    #pragma unroll
    for (int i = 0; i < 16; ++i) vzero[i] = 0.0f;

    // ---- L1 ----
    {
        const bf16x8* Bg = (const bf16x8*)wp + S_OW1 * 512;
        acc[0] = vzero; acc[1] = vzero;
        bf16x8 bc0 = Bg[(ct0 + 0) * 64 + lane];
        bf16x8 bc1 = Bg[(ct0 + 1) * 64 + lane];
        bf16x8 ac  = *(const bf16x8*)&s_a[shx(lm, lh * 8)];
        #pragma unroll
        for (int kt = 0; kt < 16; ++kt) {
            const int kn = (kt + 1) & 15;
            bf16x8 bn0 = Bg[(kn * 8 + ct0 + 0) * 64 + lane];
            bf16x8 bn1 = Bg[(kn * 8 + ct0 + 1) * 64 + lane];
            bf16x8 an  = *(const bf16x8*)&s_a[shx(lm, kn * 16 + lh * 8)];
            acc[0] = __builtin_amdgcn_mfma_f32_32x32x16_bf16(bc0, ac, acc[0], 0, 0, 0);
            acc[1] = __builtin_amdgcn_mfma_f32_32x32x16_bf16(bc1, ac, acc[1], 0, 0, 0);
            bc0 = bn0; bc1 = bn1; ac = an;
        }
        #pragma unroll
        for (int c = 0; c < 2; ++c) {
            const float* bias = &ob1[(ct0 + c) * 32 + 4 * lh];
            #pragma unroll
            for (int g = 0; g < 4; ++g) {
                bf16x4 v;
                #pragma unroll
                for (int q = 0; q < 4; ++q)
                    v[q] = (__bf16)fmaxf(acc[c][g * 4 + q] + bias[8 * g + q], 0.0f);
                *(bf16x4*)&s_h[(lm << 8) + (((((ct0 + c) << 2) + g) ^ lm) << 3) + 4 * lh] = v;
            }
        }
    }
    __syncthreads();

    // ---- L2 ----
    {
        const bf16x8* Bg = (const bf16x8*)wp + S_OW2 * 512;
        acc[0] = vzero; acc[1] = vzero;
        bf16x8 bc0 = Bg[(ct0 + 0) * 64 + lane];
        bf16x8 bc1 = Bg[(ct0 + 1) * 64 + lane];
        bf16x8 ac  = *(const bf16x8*)&s_h[shx(lm, lh * 8)];
        #pragma unroll
        for (int kt = 0; kt < 16; ++kt) {
            const int kn = (kt + 1) & 15;
            bf16x8 bn0 = Bg[(kn * 8 + ct0 + 0) * 64 + lane];
            bf16x8 bn1 = Bg[(kn * 8 + ct0 + 1) * 64 + lane];
            bf16x8 an  = *(const bf16x8*)&s_h[shx(lm, kn * 16 + lh * 8)];
            acc[0] = __builtin_amdgcn_mfma_f32_32x32x16_bf16(bc0, ac, acc[0], 0, 0, 0);
            acc[1] = __builtin_amdgcn_mfma_f32_32x32x16_bf16(bc1, ac, acc[1], 0, 0, 0);
            bc0 = bn0; bc1 = bn1; ac = an;
        }
        #pragma unroll
        for (int c = 0; c < 2; ++c) {
            const float* bias = &ob2[(ct0 + c) * 32 + 4 * lh];
            float* dstg = &out[(size_t)(b0 + lm) * OUTC + (ct0 + c) * 32 + 4 * lh];
            #pragma unroll
            for (int g = 0; g < 4; ++g) {
                float4 fv; bf16x4 v;
                float* fp = &fv.x;
                #pragma unroll
                for (int q = 0; q < 4; ++q) {
                    const float f = acc[c][g * 4 + q] + bias[8 * g + q];
                    fp[q] = f; v[q] = (__bf16)f;
                }
                *(float4*)&dstg[8 * g] = fv;
                *(bf16x4*)&s_a[(lm << 8) + (((((ct0 + c) << 2) + g) ^ lm) << 3) + 4 * lh] = v;
            }
        }
    }
    __syncthreads();

    // ---- L3 ----
    {
        const bf16x8* Bg = (const bf16x8*)wp + S_WQ * 512;
        acc[0] = vzero; acc[1] = vzero;
        bf16x8 bc0 = Bg[(ct0 + 0) * 64 + lane];
        bf16x8 bc1 = Bg[(ct0 + 1) * 64 + lane];
        bf16x8 ac  = *(const bf16x8*)&s_a[shx(lm, lh * 8)];
        #pragma unroll
        for (int kt = 0; kt < 16; ++kt) {
            const int kn = (kt + 1) & 15;
            bf16x8 bn0 = Bg[(kn * 8 + ct0 + 0) * 64 + lane];
            bf16x8 bn1 = Bg[(kn * 8 + ct0 + 1) * 64 + lane];
            bf16x8 an  = *(const bf16x8*)&s_a[shx(lm, kn * 16 + lh * 8)];
            acc[0] = __builtin_amdgcn_mfma_f32_32x32x16_bf16(bc0, ac, acc[0], 0, 0, 0);
            acc[1] = __builtin_amdgcn_mfma_f32_32x32x16_bf16(bc1, ac, acc[1], 0, 0, 0);
            bc0 = bn0; bc1 = bn1; ac = an;
        }
        #pragma unroll
        for (int c = 0; c < 2; ++c) {
            const float* bias = &bq[(ct0 + c) * 32 + 4 * lh];
            float* dstg = &qg[(size_t)(b0 + lm) * 256 + (ct0 + c) * 32 + 4 * lh];
            #pragma unroll
            for (int g = 0; g < 4; ++g) {
                float4 fv;
                float* fp = &fv.x;
                #pragma unroll
                for (int q = 0; q < 4; ++q)
                    fp[q] = acc[c][g * 4 + q] + bias[8 * g + q];
                *(float4*)&dstg[8 * g] = fv;
            }
        }
    }
}

// ---------------------------------------------------------------------------
// k_obj: M=128 (2 batch rows)/WG, 512 thr (8 waves), 2048 WGs, ~79 KB LDS
// -> 2 WGs/CU (16 waves). Wave tile 64x64: rtp=wv&1 (rows), ct0=(wv>>1)*2.
// acc = 2x2 f32x16 = 64 regs; depth-1 rotation on B (global/L2) + A (LDS).
// ---------------------------------------------------------------------------
__global__ __launch_bounds__(512, 4) void k_obj(
    const float* __restrict__ obs,  const __bf16* __restrict__ wp,
    const float* __restrict__ pb1,  const float* __restrict__ pb2,
    const float* __restrict__ pb3,  const float* __restrict__ qg,
    const float* __restrict__ bk,   const float* __restrict__ Wk,
    const float* __restrict__ bv,   const float* __restrict__ Wv,
    float* __restrict__ out)
{
    __shared__ __align__(16) __bf16 s_h[128 * 256];   // 65536 B (swizzled)
    __shared__ __align__(16) char s_fp[128 * 40 * 2]; // 10240 B: feats, later p
    __bf16* s_f = (__bf16*)s_fp;
    float*  s_p = (float*)s_fp;
    __shared__ float s_mask[128];
    __shared__ float s_qk[8 * 64];
    __shared__ float s_am[8 * 64];
    __shared__ float s_amsum[8];

    const int t  = threadIdx.x;
    const int b0 = blockIdx.x * 2;
    const int wv = t >> 6, lane = t & 63;
    const int lm = lane & 31, lh = lane >> 5;
    const int rtp = wv & 1;              // row-tile pair: rows rtp*64 .. +63
    const int ct0 = (wv >> 1) * 2;       // col tiles ct0, ct0+1
    const int row0 = rtp * 64 + lm;      // rows this lane touches
    const int row1 = row0 + 32;

    // stage 128 object rows x 32 feats as bf16 (stride 40) + mask col
    {
        const int row = t >> 2, q4 = t & 3;
        const float* src = obs + (size_t)(b0 + (row >> 6)) * OBS_COLS
                               + (row & 63) * 32 + q4 * 8;
        const float4 v0 = ((const float4*)src)[0];
        const float4 v1 = ((const float4*)src)[1];
        bf16x8 o;
        o[0]=(__bf16)v0.x; o[1]=(__bf16)v0.y; o[2]=(__bf16)v0.z; o[3]=(__bf16)v0.w;
        o[4]=(__bf16)v1.x; o[5]=(__bf16)v1.y; o[6]=(__bf16)v1.z; o[7]=(__bf16)v1.w;
        *(bf16x8*)&s_f[row * 40 + q4 * 8] = o;
        if (q4 == 3) s_mask[row] = v1.w;
    }
    __syncthreads();

    f32x16 acc[2][2];
    f32x16 vzero;
    #pragma unroll
    for (int i = 0; i < 16; ++i) vzero[i] = 0.0f;

    // ========== GEMM1: h1 = relu(feats @ W1p + b1), K=32 ==========
    {
        const bf16x8* Bg = (const bf16x8*)wp + S_PW1 * 512;
        #pragma unroll
        for (int r = 0; r < 2; ++r)
            #pragma unroll
            for (int c = 0; c < 2; ++c) acc[r][c] = vzero;
        bf16x8 b1[2][2], a1[2][2];
        #pragma unroll
        for (int kt = 0; kt < 2; ++kt) {
            #pragma unroll
            for (int c = 0; c < 2; ++c)
                b1[kt][c] = Bg[(kt * 8 + ct0 + c) * 64 + lane];
            a1[kt][0] = *(const bf16x8*)&s_f[row0 * 40 + kt * 16 + lh * 8];
            a1[kt][1] = *(const bf16x8*)&s_f[row1 * 40 + kt * 16 + lh * 8];
        }
        #pragma unroll
        for (int kt = 0; kt < 2; ++kt)
            #pragma unroll
            for (int c = 0; c < 2; ++c) {
                acc[0][c] = __builtin_amdgcn_mfma_f32_32x32x16_bf16(b1[kt][c], a1[kt][0], acc[0][c], 0, 0, 0);
                acc[1][c] = __builtin_amdgcn_mfma_f32_32x32x16_bf16(b1[kt][c], a1[kt][1], acc[1][c], 0, 0, 0);
            }
        #pragma unroll
        for (int r = 0; r < 2; ++r) {
            const int row = r ? row1 : row0;
            #pragma unroll
            for (int c = 0; c < 2; ++c) {
                const float* bias = &pb1[(ct0 + c) * 32 + 4 * lh];
                #pragma unroll
                for (int g = 0; g < 4; ++g) {
                    bf16x4 v;
                    #pragma unroll
                    for (int q = 0; q < 4; ++q)
                        v[q] = (__bf16)fmaxf(acc[r][c][g * 4 + q] + bias[8 * g + q], 0.0f);
                    *(bf16x4*)&s_h[(row << 8) + (((((ct0 + c) << 2) + g) ^ lm) << 3) + 4 * lh] = v;
                }
            }
        }
    }
    __syncthreads();

    // ========== GEMM2: h2 = relu(h1 @ W2 + b2), K=256 ==========
    {
        const bf16x8* Bg = (const bf16x8*)wp + S_PW2 * 512;
        #pragma unroll
        for (int r = 0; r < 2; ++r)
            #pragma unroll
            for (int c = 0; c < 2; ++c) acc[r][c] = vzero;
        bf16x8 bc0 = Bg[(ct0 + 0) * 64 + lane];
        bf16x8 bc1 = Bg[(ct0 + 1) * 64 + lane];
        bf16x8 a0  = *(const bf16x8*)&s_h[(row0 << 8) + ((lh ^ lm) << 3)];
        bf16x8 a1  = *(const bf16x8*)&s_h[(row1 << 8) + ((lh ^ lm) << 3)];
        #pragma unroll
        for (int kt = 0; kt < 16; ++kt) {
            const int kn = (kt + 1) & 15;
            bf16x8 bn0 = Bg[(kn * 8 + ct0 + 0) * 64 + lane];
            bf16x8 bn1 = Bg[(kn * 8 + ct0 + 1) * 64 + lane];
            bf16x8 an0 = *(const bf16x8*)&s_h[(row0 << 8) + (((2 * kn + lh) ^ lm) << 3)];
            bf16x8 an1 = *(const bf16x8*)&s_h[(row1 << 8) + (((2 * kn + lh) ^ lm) << 3)];
            acc[0][0] = __builtin_amdgcn_mfma_f32_32x32x16_bf16(bc0, a0, acc[0][0], 0, 0, 0);
            acc[0][1] = __builtin_amdgcn_mfma_f32_32x32x16_bf16(bc1, a0, acc[0][1], 0, 0, 0);
            acc[1][0] = __builtin_amdgcn_mfma_f32_32x32x16_bf16(bc0, a1, acc[1][0], 0, 0, 0);
            acc[1][1] = __builtin_amdgcn_mfma_f32_32x32x16_bf16(bc1, a1, acc[1][1], 0, 0, 0);
            bc0 = bn0; bc1 = bn1; a0 = an0; a1 = an1;
        }
        __syncthreads();   // all reads of h1 done before in-place overwrite
        #pragma unroll
        for (int r = 0; r < 2; ++r) {
            const int row = r ? row1 : row0;
            #pragma unroll
            for (int c = 0; c < 2; ++c) {
                const float* bias = &pb2[(ct0 + c) * 32 + 4 * lh];
                #pragma unroll
                for (int g = 0; g < 4; ++g) {
                    bf16x4 v;
                    #pragma unroll
                    for (int q = 0; q < 4; ++q)
                        v[q] = (__bf16)fmaxf(acc[r][c][g * 4 + q] + bias[8 * g + q], 0.0f);
                    *(bf16x4*)&s_h[(row << 8) + (((((ct0 + c) << 2) + g) ^ lm) << 3) + 4 * lh] = v;
                }
            }
        }
    }
    __syncthreads();

    // ========== GEMM3: E = (h2 @ W3 + b3) * mask, K=256 ==========
    {
        const bf16x8* Bg = (const bf16x8*)wp + S_PW3 * 512;
        #pragma unroll
        for (int r = 0; r < 2; ++r)
            #pragma unroll
            for (int c = 0; c < 2; ++c) acc[r][c] = vzero;
        bf16x8 bc0 = Bg[(ct0 + 0) * 64 + lane];
        bf16x8 bc1 = Bg[(ct0 + 1) * 64 + lane];
        bf16x8 a0  = *(const bf16x8*)&s_h[(row0 << 8) + ((lh ^ lm) << 3)];
        bf16x8 a1  = *(const bf16x8*)&s_h[(row1 << 8) + ((lh ^ lm) << 3)];
        #pragma unroll
        for (int kt = 0; kt < 16; ++kt) {
            const int kn = (kt + 1) & 15;
            bf16x8 bn0 = Bg[(kn * 8 + ct0 + 0) * 64 + lane];
            bf16x8 bn1 = Bg[(kn * 8 + ct0 + 1) * 64 + lane];
            bf16x8 an0 = *(const bf16x8*)&s_h[(row0 << 8) + (((2 * kn + lh) ^ lm) << 3)];
            bf16x8 an1 = *(const bf16x8*)&s_h[(row1 << 8) + (((2 * kn + lh) ^ lm) << 3)];
            acc[0][0] = __builtin_amdgcn_mfma_f32_32x32x16_bf16(bc0, a0, acc[0][0], 0, 0, 0);
            acc[0][1] = __builtin_amdgcn_mfma_f32_32x32x16_bf16(bc1, a0, acc[0][1], 0, 0, 0);
            acc[1][0] = __builtin_amdgcn_mfma_f32_32x32x16_bf16(bc0, a1, acc[1][0], 0, 0, 0);
            acc[1][1] = __builtin_amdgcn_mfma_f32_32x32x16_bf16(bc1, a1, acc[1][1], 0, 0, 0);
            bc0 = bn0; bc1 = bn1; a0 = an0; a1 = an1;
        }
        __syncthreads();
        #pragma unroll
        for (int r = 0; r < 2; ++r) {
            const int row = r ? row1 : row0;
            const float mk = s_mask[row];
            #pragma unroll
            for (int c = 0; c < 2; ++c) {
                const float* bias = &pb3[(ct0 + c) * 32 + 4 * lh];
                #pragma unroll
                for (int g = 0; g < 4; ++g) {
                    bf16x4 v;
                    #pragma unroll
                    for (int q = 0; q < 4; ++q)
                        v[q] = (__bf16)((acc[r][c][g * 4 + q] + bias[8 * g + q]) * mk);
                    *(bf16x4*)&s_h[(row << 8) + (((((ct0 + c) << 2) + g) ^ lm) << 3) + 4 * lh] = v;
                }
            }
        }
    }
    __syncthreads();

    // ---- Phase A: qk[r][h][d] = sum_e Wk[h][d][e] * q[r][h][e] (512 units) ----
    {
        const int r = t >> 8, h = (t >> 6) & 3, d = t & 63;
        const float* wkr = Wk + ((size_t)h * 64 + d) * 64;
        const float* q_r = qg + (size_t)(b0 + r) * 256 + h * 64;
        float a = 0.0f;
        for (int e = 0; e < 64; e += 4) {
            const float4 w = *(const float4*)&wkr[e];
            const float4 q = *(const float4*)&q_r[e];
            a += w.x * q.x + w.y * q.y + w.z * q.z + w.w * q.w;
        }
        s_qk[(r * 4 + h) * 64 + d] = a;
    }
    __syncthreads();

    // ---- Phase B: logits + softmax (wave = one (r,h) unit; lane = object) ----
    {
        const int r = wv >> 2, h = wv & 3;
        const float* q_r = qg + (size_t)(b0 + r) * 256 + h * 64;
        float qb = q_r[lane] * bk[h * 64 + lane];
        #pragma unroll
        for (int off = 32; off > 0; off >>= 1) qb += __shfl_xor(qb, off, 64);
        const int erow = r * 64 + lane;
        float dot = 0.0f;
        #pragma unroll
        for (int d8 = 0; d8 < 8; ++d8) {
            const bf16x8 ev = *(const bf16x8*)&s_h[(erow << 8) + ((((h << 3) + d8) ^ (erow & 31)) << 3)];
            const float* kv = &s_qk[(r * 4 + h) * 64 + d8 * 8];
            #pragma unroll
            for (int j = 0; j < 8; ++j) dot += (float)ev[j] * kv[j];
        }
        const float mk = s_mask[erow];
        float logit = (dot + qb) * 0.0625f;
        if (mk == 0.0f) logit = -1.0e9f;
        float m = logit;
        #pragma unroll
        for (int off = 32; off > 0; off >>= 1) m = fmaxf(m, __shfl_xor(m, off, 64));
        const float ex = __expf(logit - m);
        float ssum = ex;
        #pragma unroll
        for (int off = 32; off > 0; off >>= 1) ssum += __shfl_xor(ssum, off, 64);
        const float am = (ex / ssum) * mk;
        s_am[(r * 4 + h) * 64 + lane] = am;
        float ams = am;
        #pragma unroll
        for (int off = 32; off > 0; off >>= 1) ams += __shfl_xor(ams, off, 64);
        if (lane == 0) s_amsum[r * 4 + h] = ams;
    }
    __syncthreads();

    // ---- Phase C: p[r][h][d] = sum_n am * E[n][h*64+d] -> s_p ----
    {
        const int r = t >> 8, h = (t >> 6) & 3, d = t & 63;
        const float* amr = &s_am[(r * 4 + h) * 64];
        const int blkbase = (h << 3) + (d >> 3);
        const int doff = d & 7;
        float a = 0.0f;
        for (int n = 0; n < 64; ++n) {
            const int row = r * 64 + n;
            a += amr[n] * (float)s_h[(row << 8) + (((blkbase ^ (row & 31)) << 3) | doff)];
        }
        s_p[(r * 4 + h) * 64 + d] = a;
    }
    __syncthreads();

    // ---- Phase D: out_emb = p @ Wv + amsum * bv ----
    {
        const int r = t >> 8, h = (t >> 6) & 3, e = t & 63;
        float a = s_amsum[r * 4 + h] * bv[h * 64 + e];
        const float* pr  = &s_p[(r * 4 + h) * 64];
        const float* wvp = Wv + (size_t)h * 64 * 64;
        for (int d = 0; d < 64; ++d)
            a += pr[d] * wvp[d * 64 + e];
        out[(size_t)(b0 + r) * OUTC + EMB + h * 64 + e] = a;
    }
}

extern "C" void kernel_launch(void* const* d_in, const int* in_sizes, int n_in,
                              void* d_out, int out_size, void* d_ws, size_t ws_size,
                              hipStream_t stream)
{
    const float* obs = (const float*)d_in[0];
    const float* oW1 = (const float*)d_in[1];
    const float* ob1 = (const float*)d_in[2];
    const float* oW2 = (const float*)d_in[3];
    const float* ob2 = (const float*)d_in[4];
    const float* pW1 = (const float*)d_in[5];
    const float* pb1 = (const float*)d_in[6];
    const float* pW2 = (const float*)d_in[7];
    const float* pb2 = (const float*)d_in[8];
    const float* pW3 = (const float*)d_in[9];
    const float* pb3 = (const float*)d_in[10];
    const float* Wq  = (const float*)d_in[11];
    const float* bq  = (const float*)d_in[12];
    const float* Wk  = (const float*)d_in[13];
    const float* bk  = (const float*)d_in[14];
    const float* Wv  = (const float*)d_in[15];
    const float* bv  = (const float*)d_in[16];
    float*  out = (float*)d_out;
    float*  qg  = (float*)d_ws;
    __bf16* wp  = (__bf16*)((char*)d_ws + Q_BYTES);

    k_prep<<<82, 512, 0, stream>>>(pW1, pW2, pW3, oW1, oW2, Wq, wp);
    k_oth<<<BATCH / 32, 256, 0, stream>>>(obs, wp, ob1, ob2, bq, out, qg);
    k_obj<<<BATCH / 2, 512, 0, stream>>>(obs, wp, pb1, pb2, pb3, qg,
                                         bk, Wk, bv, Wv, out);
}

// Round 5
// 264.666 us; speedup vs baseline: 6.1684x; 1.0878x over previous
//
#include <hip/hip_runtime.h>

#define BATCH      4096
#define OBS_COLS   2304
#define OTH_OFF    2048
#define EMB        256
#define OUTC       512
#define Q_BYTES    (4096u * 256u * 4u)

typedef __bf16 bf16x8 __attribute__((ext_vector_type(8)));
typedef __bf16 bf16x4 __attribute__((ext_vector_type(4)));
typedef float  f32x16 __attribute__((ext_vector_type(16)));

// Slice bases (units of 512 bf16x8 = one 16x256 K-step slice)
#define S_PW1  0
#define S_PW2  2
#define S_PW3  18
#define S_OW1  34
#define S_OW2  50
#define S_WQ   66

// Swizzled element index into a [rows][256] bf16 LDS tile:
// 16-B blocks within a row are XORed with (row & 31).
__device__ __forceinline__ int shx(int row, int col) {
    return (row << 8) + ((((col >> 3) ^ (row & 31)) << 3) | (col & 7));
}

// ---------------------------------------------------------------------------
// k_prep: pack 6 weight matrices as bf16 MFMA B-fragments.
// frag elem j of (ct,lane): W[kt*16 + (lane>>5)*8 + j][ct*32 + (lane&31)].
// ---------------------------------------------------------------------------
__global__ __launch_bounds__(512) void k_prep(
    const float* __restrict__ pW1, const float* __restrict__ pW2,
    const float* __restrict__ pW3, const float* __restrict__ oW1,
    const float* __restrict__ oW2, const float* __restrict__ Wq,
    __bf16* __restrict__ wp)
{
    const int s = blockIdx.x;          // 0..81
    const int t = threadIdx.x;
    const int ct = t >> 6, lane = t & 63;
    int kt; const float* W; int isW1 = 0;
    if      (s < S_PW2) { kt = s;         W = pW1; isW1 = 1; }
    else if (s < S_PW3) { kt = s - S_PW2; W = pW2; }
    else if (s < S_OW1) { kt = s - S_PW3; W = pW3; }
    else if (s < S_OW2) { kt = s - S_OW1; W = oW1; }
    else if (s < S_WQ)  { kt = s - S_OW2; W = oW2; }
    else                { kt = s - S_WQ;  W = Wq; }
    const int kbase = kt * 16 + (lane >> 5) * 8;
    const int n     = ct * 32 + (lane & 31);
    bf16x8 v;
    #pragma unroll
    for (int j = 0; j < 8; ++j) {
        const int k = kbase + j;
        const float f = (isW1 && k >= 31) ? 0.0f : W[k * 256 + n];
        v[j] = (__bf16)f;
    }
    ((bf16x8*)wp)[(size_t)s * 512 + t] = v;
}

// ---------------------------------------------------------------------------
// k_oth: others MLP via MFMA. M=32 rows/WG, 512 thr (8 waves), 128 WGs.
// Wave wv handles ONE 32-col tile (ct = wv); acc = 16 regs. Layers fully
// unrolled so the compiler hoists the 16 B-fragment L2 loads per layer.
// ---------------------------------------------------------------------------
__global__ __launch_bounds__(512, 2) void k_oth(
    const float* __restrict__ obs, const __bf16* __restrict__ wp,
    const float* __restrict__ ob1, const float* __restrict__ ob2,
    const float* __restrict__ bq,
    float* __restrict__ out, float* __restrict__ qg)
{
    __shared__ __align__(16) __bf16 s_a[32 * 256];   // 16 KB
    __shared__ __align__(16) __bf16 s_h[32 * 256];   // 16 KB

    const int t  = threadIdx.x;
    const int b0 = blockIdx.x * 32;
    const int wv = t >> 6, lane = t & 63;
    const int lm = lane & 31, lh = lane >> 5;
    const int ct = wv;                 // col tile 0..7

    // stage 32 rows x 256 cols (fp32 -> bf16, swizzled): 1024 chunks of 8
    #pragma unroll
    for (int i = 0; i < 2; ++i) {
        const int c = i * 512 + t;
        const int row = c >> 5, seg = c & 31;
        const float* src = obs + (size_t)(b0 + row) * OBS_COLS + OTH_OFF + seg * 8;
        const float4 v0 = ((const float4*)src)[0];
        const float4 v1 = ((const float4*)src)[1];
        bf16x8 o;
        o[0]=(__bf16)v0.x; o[1]=(__bf16)v0.y; o[2]=(__bf16)v0.z; o[3]=(__bf16)v0.w;
        o[4]=(__bf16)v1.x; o[5]=(__bf16)v1.y; o[6]=(__bf16)v1.z; o[7]=(__bf16)v1.w;
        *(bf16x8*)&s_a[shx(row, seg * 8)] = o;
    }
    __syncthreads();

    f32x16 acc;
    f32x16 vzero;
    #pragma unroll
    for (int i = 0; i < 16; ++i) vzero[i] = 0.0f;

    // ---- L1: h = relu(A @ oW1 + ob1) ----
    {
        const bf16x8* Bg = (const bf16x8*)wp + S_OW1 * 512;
        acc = vzero;
        #pragma unroll
        for (int kt = 0; kt < 16; ++kt) {
            const bf16x8 b = Bg[(kt * 8 + ct) * 64 + lane];
            const bf16x8 a = *(const bf16x8*)&s_a[shx(lm, kt * 16 + lh * 8)];
            acc = __builtin_amdgcn_mfma_f32_32x32x16_bf16(b, a, acc, 0, 0, 0);
        }
        const float* bias = &ob1[ct * 32 + 4 * lh];
        #pragma unroll
        for (int g = 0; g < 4; ++g) {
            bf16x4 v;
            #pragma unroll
            for (int q = 0; q < 4; ++q)
                v[q] = (__bf16)fmaxf(acc[g * 4 + q] + bias[8 * g + q], 0.0f);
            *(bf16x4*)&s_h[(lm << 8) + ((((ct << 2) + g) ^ lm) << 3) + 4 * lh] = v;
        }
    }
    __syncthreads();

    // ---- L2: e = s_h @ oW2 + ob2 (no relu) -> out + s_a ----
    {
        const bf16x8* Bg = (const bf16x8*)wp + S_OW2 * 512;
        acc = vzero;
        #pragma unroll
        for (int kt = 0; kt < 16; ++kt) {
            const bf16x8 b = Bg[(kt * 8 + ct) * 64 + lane];
            const bf16x8 a = *(const bf16x8*)&s_h[shx(lm, kt * 16 + lh * 8)];
            acc = __builtin_amdgcn_mfma_f32_32x32x16_bf16(b, a, acc, 0, 0, 0);
        }
        const float* bias = &ob2[ct * 32 + 4 * lh];
        float* dstg = &out[(size_t)(b0 + lm) * OUTC + ct * 32 + 4 * lh];
        #pragma unroll
        for (int g = 0; g < 4; ++g) {
            float4 fv; bf16x4 v;
            float* fp = &fv.x;
            #pragma unroll
            for (int q = 0; q < 4; ++q) {
                const float f = acc[g * 4 + q] + bias[8 * g + q];
                fp[q] = f; v[q] = (__bf16)f;
            }
            *(float4*)&dstg[8 * g] = fv;
            *(bf16x4*)&s_a[(lm << 8) + ((((ct << 2) + g) ^ lm) << 3) + 4 * lh] = v;
        }
    }
    __syncthreads();

    // ---- L3: q = s_a @ Wq + bq -> qg ----
    {
        const bf16x8* Bg = (const bf16x8*)wp + S_WQ * 512;
        acc = vzero;
        #pragma unroll
        for (int kt = 0; kt < 16; ++kt) {
            const bf16x8 b = Bg[(kt * 8 + ct) * 64 + lane];
            const bf16x8 a = *(const bf16x8*)&s_a[shx(lm, kt * 16 + lh * 8)];
            acc = __builtin_amdgcn_mfma_f32_32x32x16_bf16(b, a, acc, 0, 0, 0);
        }
        const float* bias = &bq[ct * 32 + 4 * lh];
        float* dstg = &qg[(size_t)(b0 + lm) * 256 + ct * 32 + 4 * lh];
        #pragma unroll
        for (int g = 0; g < 4; ++g) {
            float4 fv;
            float* fp = &fv.x;
            #pragma unroll
            for (int q = 0; q < 4; ++q)
                fp[q] = acc[g * 4 + q] + bias[8 * g + q];
            *(float4*)&dstg[8 * g] = fv;
        }
    }
}

// ---------------------------------------------------------------------------
// k_obj: M=128 (2 batch rows)/WG, 512 thr (8 waves), 2048 WGs, ~79 KB LDS
// -> 2 WGs/CU (16 waves, 4/SIMD). Wave tile 64x64: rtp=wv&1, ct0=(wv>>1)*2.
// acc 64 regs; depth-1 rotation on B ONLY (fits the 128-reg budget -> no
// scratch spills, which were R4's 110 MB WRITE_SIZE).
// ---------------------------------------------------------------------------
__global__ __launch_bounds__(512, 4) void k_obj(
    const float* __restrict__ obs,  const __bf16* __restrict__ wp,
    const float* __restrict__ pb1,  const float* __restrict__ pb2,
    const float* __restrict__ pb3,  const float* __restrict__ qg,
    const float* __restrict__ bk,   const float* __restrict__ Wk,
    const float* __restrict__ bv,   const float* __restrict__ Wv,
    float* __restrict__ out)
{
    __shared__ __align__(16) __bf16 s_h[128 * 256];   // 65536 B (swizzled)
    __shared__ __align__(16) char s_fp[128 * 40 * 2]; // 10240 B: feats, later p
    __bf16* s_f = (__bf16*)s_fp;
    float*  s_p = (float*)s_fp;
    __shared__ float s_mask[128];
    __shared__ float s_qk[8 * 64];
    __shared__ float s_am[8 * 64];
    __shared__ float s_amsum[8];

    const int t  = threadIdx.x;
    const int b0 = blockIdx.x * 2;
    const int wv = t >> 6, lane = t & 63;
    const int lm = lane & 31, lh = lane >> 5;
    const int rtp = wv & 1;
    const int ct0 = (wv >> 1) * 2;
    const int row0 = rtp * 64 + lm;
    const int row1 = row0 + 32;

    // stage 128 object rows x 32 feats as bf16 (stride 40) + mask col
    {
        const int row = t >> 2, q4 = t & 3;
        const float* src = obs + (size_t)(b0 + (row >> 6)) * OBS_COLS
                               + (row & 63) * 32 + q4 * 8;
        const float4 v0 = ((const float4*)src)[0];
        const float4 v1 = ((const float4*)src)[1];
        bf16x8 o;
        o[0]=(__bf16)v0.x; o[1]=(__bf16)v0.y; o[2]=(__bf16)v0.z; o[3]=(__bf16)v0.w;
        o[4]=(__bf16)v1.x; o[5]=(__bf16)v1.y; o[6]=(__bf16)v1.z; o[7]=(__bf16)v1.w;
        *(bf16x8*)&s_f[row * 40 + q4 * 8] = o;
        if (q4 == 3) s_mask[row] = v1.w;
    }
    __syncthreads();

    f32x16 acc[2][2];
    f32x16 vzero;
    #pragma unroll
    for (int i = 0; i < 16; ++i) vzero[i] = 0.0f;

    // ========== GEMM1: h1 = relu(feats @ W1p + b1), K=32 (streamed) ==========
    {
        const bf16x8* Bg = (const bf16x8*)wp + S_PW1 * 512;
        #pragma unroll
        for (int r = 0; r < 2; ++r)
            #pragma unroll
            for (int c = 0; c < 2; ++c) acc[r][c] = vzero;
        #pragma unroll
        for (int kt = 0; kt < 2; ++kt) {
            const bf16x8 bf0 = Bg[(kt * 8 + ct0 + 0) * 64 + lane];
            const bf16x8 bf1 = Bg[(kt * 8 + ct0 + 1) * 64 + lane];
            const bf16x8 a0 = *(const bf16x8*)&s_f[row0 * 40 + kt * 16 + lh * 8];
            const bf16x8 a1 = *(const bf16x8*)&s_f[row1 * 40 + kt * 16 + lh * 8];
            acc[0][0] = __builtin_amdgcn_mfma_f32_32x32x16_bf16(bf0, a0, acc[0][0], 0, 0, 0);
            acc[0][1] = __builtin_amdgcn_mfma_f32_32x32x16_bf16(bf1, a0, acc[0][1], 0, 0, 0);
            acc[1][0] = __builtin_amdgcn_mfma_f32_32x32x16_bf16(bf0, a1, acc[1][0], 0, 0, 0);
            acc[1][1] = __builtin_amdgcn_mfma_f32_32x32x16_bf16(bf1, a1, acc[1][1], 0, 0, 0);
        }
        #pragma unroll
        for (int r = 0; r < 2; ++r) {
            const int row = r ? row1 : row0;
            #pragma unroll
            for (int c = 0; c < 2; ++c) {
                const float* bias = &pb1[(ct0 + c) * 32 + 4 * lh];
                #pragma unroll
                for (int g = 0; g < 4; ++g) {
                    bf16x4 v;
                    #pragma unroll
                    for (int q = 0; q < 4; ++q)
                        v[q] = (__bf16)fmaxf(acc[r][c][g * 4 + q] + bias[8 * g + q], 0.0f);
                    *(bf16x4*)&s_h[(row << 8) + (((((ct0 + c) << 2) + g) ^ lm) << 3) + 4 * lh] = v;
                }
            }
        }
    }
    __syncthreads();

    // ========== GEMM2: h2 = relu(h1 @ W2 + b2), K=256 ==========
    {
        const bf16x8* Bg = (const bf16x8*)wp + S_PW2 * 512;
        #pragma unroll
        for (int r = 0; r < 2; ++r)
            #pragma unroll
            for (int c = 0; c < 2; ++c) acc[r][c] = vzero;
        bf16x8 bc0 = Bg[(ct0 + 0) * 64 + lane];
        bf16x8 bc1 = Bg[(ct0 + 1) * 64 + lane];
        #pragma unroll 4
        for (int kt = 0; kt < 16; ++kt) {
            const int kn = (kt + 1) & 15;
            const bf16x8 bn0 = Bg[(kn * 8 + ct0 + 0) * 64 + lane];
            const bf16x8 bn1 = Bg[(kn * 8 + ct0 + 1) * 64 + lane];
            const bf16x8 a0 = *(const bf16x8*)&s_h[(row0 << 8) + (((2 * kt + lh) ^ lm) << 3)];
            const bf16x8 a1 = *(const bf16x8*)&s_h[(row1 << 8) + (((2 * kt + lh) ^ lm) << 3)];
            acc[0][0] = __builtin_amdgcn_mfma_f32_32x32x16_bf16(bc0, a0, acc[0][0], 0, 0, 0);
            acc[0][1] = __builtin_amdgcn_mfma_f32_32x32x16_bf16(bc1, a0, acc[0][1], 0, 0, 0);
            acc[1][0] = __builtin_amdgcn_mfma_f32_32x32x16_bf16(bc0, a1, acc[1][0], 0, 0, 0);
            acc[1][1] = __builtin_amdgcn_mfma_f32_32x32x16_bf16(bc1, a1, acc[1][1], 0, 0, 0);
            bc0 = bn0; bc1 = bn1;
        }
        __syncthreads();   // all reads of h1 done before in-place overwrite
        #pragma unroll
        for (int r = 0; r < 2; ++r) {
            const int row = r ? row1 : row0;
            #pragma unroll
            for (int c = 0; c < 2; ++c) {
                const float* bias = &pb2[(ct0 + c) * 32 + 4 * lh];
                #pragma unroll
                for (int g = 0; g < 4; ++g) {
                    bf16x4 v;
                    #pragma unroll
                    for (int q = 0; q < 4; ++q)
                        v[q] = (__bf16)fmaxf(acc[r][c][g * 4 + q] + bias[8 * g + q], 0.0f);
                    *(bf16x4*)&s_h[(row << 8) + (((((ct0 + c) << 2) + g) ^ lm) << 3) + 4 * lh] = v;
                }
            }
        }
    }
    __syncthreads();

    // ========== GEMM3: E = (h2 @ W3 + b3) * mask, K=256 ==========
    {
        const bf16x8* Bg = (const bf16x8*)wp + S_PW3 * 512;
        #pragma unroll
        for (int r = 0; r < 2; ++r)
            #pragma unroll
            for (int c = 0; c < 2; ++c) acc[r][c] = vzero;
        bf16x8 bc0 = Bg[(ct0 + 0) * 64 + lane];
        bf16x8 bc1 = Bg[(ct0 + 1) * 64 + lane];
        #pragma unroll 4
        for (int kt = 0; kt < 16; ++kt) {
            const int kn = (kt + 1) & 15;
            const bf16x8 bn0 = Bg[(kn * 8 + ct0 + 0) * 64 + lane];
            const bf16x8 bn1 = Bg[(kn * 8 + ct0 + 1) * 64 + lane];
            const bf16x8 a0 = *(const bf16x8*)&s_h[(row0 << 8) + (((2 * kt + lh) ^ lm) << 3)];
            const bf16x8 a1 = *(const bf16x8*)&s_h[(row1 << 8) + (((2 * kt + lh) ^ lm) << 3)];
            acc[0][0] = __builtin_amdgcn_mfma_f32_32x32x16_bf16(bc0, a0, acc[0][0], 0, 0, 0);
            acc[0][1] = __builtin_amdgcn_mfma_f32_32x32x16_bf16(bc1, a0, acc[0][1], 0, 0, 0);
            acc[1][0] = __builtin_amdgcn_mfma_f32_32x32x16_bf16(bc0, a1, acc[1][0], 0, 0, 0);
            acc[1][1] = __builtin_amdgcn_mfma_f32_32x32x16_bf16(bc1, a1, acc[1][1], 0, 0, 0);
            bc0 = bn0; bc1 = bn1;
        }
        __syncthreads();
        #pragma unroll
        for (int r = 0; r < 2; ++r) {
            const int row = r ? row1 : row0;
            const float mk = s_mask[row];
            #pragma unroll
            for (int c = 0; c < 2; ++c) {
                const float* bias = &pb3[(ct0 + c) * 32 + 4 * lh];
                #pragma unroll
                for (int g = 0; g < 4; ++g) {
                    bf16x4 v;
                    #pragma unroll
                    for (int q = 0; q < 4; ++q)
                        v[q] = (__bf16)((acc[r][c][g * 4 + q] + bias[8 * g + q]) * mk);
                    *(bf16x4*)&s_h[(row << 8) + (((((ct0 + c) << 2) + g) ^ lm) << 3) + 4 * lh] = v;
                }
            }
        }
    }
    __syncthreads();

    // ---- Phase A: qk[r][h][d] = sum_e Wk[h][d][e] * q[r][h][e] ----
    {
        const int r = t >> 8, h = (t >> 6) & 3, d = t & 63;
        const float* wkr = Wk + ((size_t)h * 64 + d) * 64;
        const float* q_r = qg + (size_t)(b0 + r) * 256 + h * 64;
        float a = 0.0f;
        for (int e = 0; e < 64; e += 4) {
            const float4 w = *(const float4*)&wkr[e];
            const float4 q = *(const float4*)&q_r[e];
            a += w.x * q.x + w.y * q.y + w.z * q.z + w.w * q.w;
        }
        s_qk[(r * 4 + h) * 64 + d] = a;
    }
    __syncthreads();

    // ---- Phase B: logits + softmax (wave = one (r,h) unit; lane = object) ----
    {
        const int r = wv >> 2, h = wv & 3;
        const float* q_r = qg + (size_t)(b0 + r) * 256 + h * 64;
        float qb = q_r[lane] * bk[h * 64 + lane];
        #pragma unroll
        for (int off = 32; off > 0; off >>= 1) qb += __shfl_xor(qb, off, 64);
        const int erow = r * 64 + lane;
        float dot = 0.0f;
        #pragma unroll
        for (int d8 = 0; d8 < 8; ++d8) {
            const bf16x8 ev = *(const bf16x8*)&s_h[(erow << 8) + ((((h << 3) + d8) ^ (erow & 31)) << 3)];
            const float* kv = &s_qk[(r * 4 + h) * 64 + d8 * 8];
            #pragma unroll
            for (int j = 0; j < 8; ++j) dot += (float)ev[j] * kv[j];
        }
        const float mk = s_mask[erow];
        float logit = (dot + qb) * 0.0625f;
        if (mk == 0.0f) logit = -1.0e9f;
        float m = logit;
        #pragma unroll
        for (int off = 32; off > 0; off >>= 1) m = fmaxf(m, __shfl_xor(m, off, 64));
        const float ex = __expf(logit - m);
        float ssum = ex;
        #pragma unroll
        for (int off = 32; off > 0; off >>= 1) ssum += __shfl_xor(ssum, off, 64);
        const float am = (ex / ssum) * mk;
        s_am[(r * 4 + h) * 64 + lane] = am;
        float ams = am;
        #pragma unroll
        for (int off = 32; off > 0; off >>= 1) ams += __shfl_xor(ams, off, 64);
        if (lane == 0) s_amsum[r * 4 + h] = ams;
    }
    __syncthreads();

    // ---- Phase C: p[r][h][d] = sum_n am * E[n][h*64+d] -> s_p ----
    {
        const int r = t >> 8, h = (t >> 6) & 3, d = t & 63;
        const float* amr = &s_am[(r * 4 + h) * 64];
        const int blkbase = (h << 3) + (d >> 3);
        const int doff = d & 7;
        float a = 0.0f;
        for (int n = 0; n < 64; ++n) {
            const int row = r * 64 + n;
            a += amr[n] * (float)s_h[(row << 8) + (((blkbase ^ (row & 31)) << 3) | doff)];
        }
        s_p[(r * 4 + h) * 64 + d] = a;
    }
    __syncthreads();

    // ---- Phase D: out_emb = p @ Wv + amsum * bv ----
    {
        const int r = t >> 8, h = (t >> 6) & 3, e = t & 63;
        float a = s_amsum[r * 4 + h] * bv[h * 64 + e];
        const float* pr  = &s_p[(r * 4 + h) * 64];
        const float* wvp = Wv + (size_t)h * 64 * 64;
        for (int d = 0; d < 64; ++d)
            a += pr[d] * wvp[d * 64 + e];
        out[(size_t)(b0 + r) * OUTC + EMB + h * 64 + e] = a;
    }
}

extern "C" void kernel_launch(void* const* d_in, const int* in_sizes, int n_in,
                              void* d_out, int out_size, void* d_ws, size_t ws_size,
                              hipStream_t stream)
{
    const float* obs = (const float*)d_in[0];
    const float* oW1 = (const float*)d_in[1];
    const float* ob1 = (const float*)d_in[2];
    const float* oW2 = (const float*)d_in[3];
    const float* ob2 = (const float*)d_in[4];
    const float* pW1 = (const float*)d_in[5];
    const float* pb1 = (const float*)d_in[6];
    const float* pW2 = (const float*)d_in[7];
    const float* pb2 = (const float*)d_in[8];
    const float* pW3 = (const float*)d_in[9];
    const float* pb3 = (const float*)d_in[10];
    const float* Wq  = (const float*)d_in[11];
    const float* bq  = (const float*)d_in[12];
    const float* Wk  = (const float*)d_in[13];
    const float* bk  = (const float*)d_in[14];
    const float* Wv  = (const float*)d_in[15];
    const float* bv  = (const float*)d_in[16];
    float*  out = (float*)d_out;
    float*  qg  = (float*)d_ws;
    __bf16* wp  = (__bf16*)((char*)d_ws + Q_BYTES);

    k_prep<<<82, 512, 0, stream>>>(pW1, pW2, pW3, oW1, oW2, Wq, wp);
    k_oth<<<BATCH / 32, 512, 0, stream>>>(obs, wp, ob1, ob2, bq, out, qg);
    k_obj<<<BATCH / 2, 512, 0, stream>>>(obs, wp, pb1, pb2, pb3, qg,
                                         bk, Wk, bv, Wv, out);
}

// Round 6
// 229.579 us; speedup vs baseline: 7.1112x; 1.1528x over previous
//
#include <hip/hip_runtime.h>

#define BATCH      4096
#define OBS_COLS   2304
#define OTH_OFF    2048
#define EMB        256
#define OUTC       512

// ws layout: qk (4096x256 f32) | qb (4096x4 f32) | packed pW slices (34 x 8KB)
#define QK_BYTES   (4096u * 256u * 4u)
#define QB_BYTES   (4096u * 4u * 4u)

typedef __bf16 bf16x8 __attribute__((ext_vector_type(8)));
typedef __bf16 bf16x4 __attribute__((ext_vector_type(4)));
typedef float  f32x16 __attribute__((ext_vector_type(16)));

// Slice bases (units of 512 bf16x8 = one 16x256 K-step slice) within wp
#define S_PW1  0
#define S_PW2  2
#define S_PW3  18
#define N_SLICE 34

// Swizzled element index into a [rows][256] bf16 LDS tile.
__device__ __forceinline__ int shx(int row, int col) {
    return (row << 8) + ((((col >> 3) ^ (row & 31)) << 3) | (col & 7));
}

// ---------------------------------------------------------------------------
// k_oth: 128 WGs x 512 thr.
//  - WGs 0..33 additionally pack one pW slice into wp (for k_obj).
//  - others MLP (M=32/WG) with B-fragments read directly from fp32 weights
//    (8 coalesced dword loads, depth-1 rotation), A staged in LDS.
//  - L3 computes q, then qk = Wk.q (4 MFMAs/wave) and qb = q.bk -> ws.
// ---------------------------------------------------------------------------
__global__ __launch_bounds__(512, 2) void k_oth(
    const float* __restrict__ obs,
    const float* __restrict__ oW1, const float* __restrict__ ob1,
    const float* __restrict__ oW2, const float* __restrict__ ob2,
    const float* __restrict__ Wq,  const float* __restrict__ bq,
    const float* __restrict__ Wk,  const float* __restrict__ bk,
    const float* __restrict__ pW1, const float* __restrict__ pW2,
    const float* __restrict__ pW3,
    float* __restrict__ out, float* __restrict__ qkg,
    float* __restrict__ qbg, __bf16* __restrict__ wp)
{
    __shared__ __align__(16) __bf16 s_a[32 * 256];   // 16 KB
    __shared__ __align__(16) __bf16 s_h[32 * 256];   // 16 KB
    __shared__ __align__(16) __bf16 s_q[32 * 256];   // 16 KB
    __shared__ float s_qb[32 * 4];

    const int t  = threadIdx.x;
    const int b0 = blockIdx.x * 32;
    const int wv = t >> 6, lane = t & 63;
    const int lm = lane & 31, lh = lane >> 5;
    const int ct = wv;                 // col tile 0..7

    // ---- pack pW slices for k_obj (WGs 0..33) ----
    if (blockIdx.x < N_SLICE) {
        const int s = blockIdx.x;
        int kt; const float* W; int isW1 = 0;
        if      (s < S_PW2) { kt = s;         W = pW1; isW1 = 1; }
        else if (s < S_PW3) { kt = s - S_PW2; W = pW2; }
        else                { kt = s - S_PW3; W = pW3; }
        const int kbase = kt * 16 + lh * 8;
        const int n     = (t >> 6) * 32 + lm;   // ct*32 + lm
        bf16x8 v;
        #pragma unroll
        for (int j = 0; j < 8; ++j) {
            const int k = kbase + j;
            const float f = (isW1 && k >= 31) ? 0.0f : W[k * 256 + n];
            v[j] = (__bf16)f;
        }
        ((bf16x8*)wp)[(size_t)s * 512 + t] = v;
    }

    // ---- stage 32 rows x 256 cols (fp32 -> bf16, swizzled) ----
    #pragma unroll
    for (int i = 0; i < 2; ++i) {
        const int c = i * 512 + t;
        const int row = c >> 5, seg = c & 31;
        const float* src = obs + (size_t)(b0 + row) * OBS_COLS + OTH_OFF + seg * 8;
        const float4 v0 = ((const float4*)src)[0];
        const float4 v1 = ((const float4*)src)[1];
        bf16x8 o;
        o[0]=(__bf16)v0.x; o[1]=(__bf16)v0.y; o[2]=(__bf16)v0.z; o[3]=(__bf16)v0.w;
        o[4]=(__bf16)v1.x; o[5]=(__bf16)v1.y; o[6]=(__bf16)v1.z; o[7]=(__bf16)v1.w;
        *(bf16x8*)&s_a[shx(row, seg * 8)] = o;
    }
    if (t < 128) s_qb[t] = 0.0f;
    __syncthreads();

    f32x16 acc;
    f32x16 vzero;
    #pragma unroll
    for (int i = 0; i < 16; ++i) vzero[i] = 0.0f;

    // ---- L1: h = relu(A @ oW1 + ob1); B direct from fp32, depth-1 rot ----
    {
        const float* Wl = oW1 + (size_t)(lh * 8) * 256 + ct * 32 + lm;
        acc = vzero;
        float f[8];
        #pragma unroll
        for (int j = 0; j < 8; ++j) f[j] = Wl[j * 256];
        #pragma unroll 4
        for (int kt = 0; kt < 16; ++kt) {
            float fn[8];
            const int kn = (kt + 1) & 15;
            #pragma unroll
            for (int j = 0; j < 8; ++j) fn[j] = Wl[(kn * 16 + j) * 256];
            bf16x8 b;
            #pragma unroll
            for (int j = 0; j < 8; ++j) b[j] = (__bf16)f[j];
            const bf16x8 a = *(const bf16x8*)&s_a[shx(lm, kt * 16 + lh * 8)];
            acc = __builtin_amdgcn_mfma_f32_32x32x16_bf16(b, a, acc, 0, 0, 0);
            #pragma unroll
            for (int j = 0; j < 8; ++j) f[j] = fn[j];
        }
        const float* bias = &ob1[ct * 32 + 4 * lh];
        #pragma unroll
        for (int g = 0; g < 4; ++g) {
            bf16x4 v;
            #pragma unroll
            for (int q = 0; q < 4; ++q)
                v[q] = (__bf16)fmaxf(acc[g * 4 + q] + bias[8 * g + q], 0.0f);
            *(bf16x4*)&s_h[(lm << 8) + ((((ct << 2) + g) ^ lm) << 3) + 4 * lh] = v;
        }
    }
    __syncthreads();

    // ---- L2: e = s_h @ oW2 + ob2 -> out (fp32) + s_a (bf16) ----
    {
        const float* Wl = oW2 + (size_t)(lh * 8) * 256 + ct * 32 + lm;
        acc = vzero;
        float f[8];
        #pragma unroll
        for (int j = 0; j < 8; ++j) f[j] = Wl[j * 256];
        #pragma unroll 4
        for (int kt = 0; kt < 16; ++kt) {
            float fn[8];
            const int kn = (kt + 1) & 15;
            #pragma unroll
            for (int j = 0; j < 8; ++j) fn[j] = Wl[(kn * 16 + j) * 256];
            bf16x8 b;
            #pragma unroll
            for (int j = 0; j < 8; ++j) b[j] = (__bf16)f[j];
            const bf16x8 a = *(const bf16x8*)&s_h[shx(lm, kt * 16 + lh * 8)];
            acc = __builtin_amdgcn_mfma_f32_32x32x16_bf16(b, a, acc, 0, 0, 0);
            #pragma unroll
            for (int j = 0; j < 8; ++j) f[j] = fn[j];
        }
        const float* bias = &ob2[ct * 32 + 4 * lh];
        float* dstg = &out[(size_t)(b0 + lm) * OUTC + ct * 32 + 4 * lh];
        #pragma unroll
        for (int g = 0; g < 4; ++g) {
            float4 fv; bf16x4 v;
            float* fp = &fv.x;
            #pragma unroll
            for (int q = 0; q < 4; ++q) {
                const float f2 = acc[g * 4 + q] + bias[8 * g + q];
                fp[q] = f2; v[q] = (__bf16)f2;
            }
            *(float4*)&dstg[8 * g] = fv;
            *(bf16x4*)&s_a[(lm << 8) + ((((ct << 2) + g) ^ lm) << 3) + 4 * lh] = v;
        }
    }
    __syncthreads();

    // ---- L3: q = s_a @ Wq + bq -> s_q (bf16) ; qb partial -> s_qb ----
    {
        const float* Wl = Wq + (size_t)(lh * 8) * 256 + ct * 32 + lm;
        acc = vzero;
        float f[8];
        #pragma unroll
        for (int j = 0; j < 8; ++j) f[j] = Wl[j * 256];
        #pragma unroll 4
        for (int kt = 0; kt < 16; ++kt) {
            float fn[8];
            const int kn = (kt + 1) & 15;
            #pragma unroll
            for (int j = 0; j < 8; ++j) fn[j] = Wl[(kn * 16 + j) * 256];
            bf16x8 b;
            #pragma unroll
            for (int j = 0; j < 8; ++j) b[j] = (__bf16)f[j];
            const bf16x8 a = *(const bf16x8*)&s_a[shx(lm, kt * 16 + lh * 8)];
            acc = __builtin_amdgcn_mfma_f32_32x32x16_bf16(b, a, acc, 0, 0, 0);
            #pragma unroll
            for (int j = 0; j < 8; ++j) f[j] = fn[j];
        }
        const int hh = ct >> 1;    // head this col-tile belongs to
        const float* bias = &bq[ct * 32 + 4 * lh];
        const float* bkp  = &bk[ct * 32 + 4 * lh];
        float part = 0.0f;
        #pragma unroll
        for (int g = 0; g < 4; ++g) {
            bf16x4 v;
            #pragma unroll
            for (int q = 0; q < 4; ++q) {
                const float f2 = acc[g * 4 + q] + bias[8 * g + q];
                part += f2 * bkp[8 * g + q];
                v[q] = (__bf16)f2;
            }
            *(bf16x4*)&s_q[(lm << 8) + ((((ct << 2) + g) ^ lm) << 3) + 4 * lh] = v;
        }
        part += __shfl_xor(part, 32, 64);
        if (lane < 32) atomicAdd(&s_qb[lm * 4 + hh], part);
    }
    __syncthreads();

    // ---- qb out ----
    if (t < 128) qbg[(size_t)(b0 + (t >> 2)) * 4 + (t & 3)] = s_qb[t];

    // ---- qk[row][h*64+d] = sum_e Wk[h][d][e]*q[row][h*64+e] via MFMA ----
    {
        const int h = wv >> 1, c2 = wv & 1;   // 8 waves = 4 heads x 2 col-tiles
        acc = vzero;
        #pragma unroll
        for (int kt = 0; kt < 4; ++kt) {
            const float* wk = Wk + ((size_t)(h * 64 + c2 * 32 + lm) * 64 + kt * 16 + lh * 8);
            const float4 w0 = *(const float4*)wk;
            const float4 w1 = *(const float4*)(wk + 4);
            bf16x8 b;
            b[0]=(__bf16)w0.x; b[1]=(__bf16)w0.y; b[2]=(__bf16)w0.z; b[3]=(__bf16)w0.w;
            b[4]=(__bf16)w1.x; b[5]=(__bf16)w1.y; b[6]=(__bf16)w1.z; b[7]=(__bf16)w1.w;
            const bf16x8 a = *(const bf16x8*)&s_q[shx(lm, h * 64 + kt * 16 + lh * 8)];
            acc = __builtin_amdgcn_mfma_f32_32x32x16_bf16(b, a, acc, 0, 0, 0);
        }
        float* dstg = &qkg[(size_t)(b0 + lm) * 256 + h * 64 + c2 * 32 + 4 * lh];
        #pragma unroll
        for (int g = 0; g < 4; ++g) {
            float4 fv;
            float* fp = &fv.x;
            #pragma unroll
            for (int q = 0; q < 4; ++q) fp[q] = acc[g * 4 + q];
            *(float4*)&dstg[8 * g] = fv;
        }
    }
}

// ---------------------------------------------------------------------------
// k_obj: M=128 (2 batch rows)/WG, 512 thr (8 waves), 2048 WGs, ~79 KB LDS
// -> 2 WGs/CU. Wave tile 64x64; acc 64 regs; depth-1 rotation on B only.
// Attention: qk/qb precomputed by k_oth; Phases C/D unrolled x16.
// ---------------------------------------------------------------------------
__global__ __launch_bounds__(512, 4) void k_obj(
    const float* __restrict__ obs,  const __bf16* __restrict__ wp,
    const float* __restrict__ pb1,  const float* __restrict__ pb2,
    const float* __restrict__ pb3,  const float* __restrict__ qkg,
    const float* __restrict__ qbg,  const float* __restrict__ bv,
    const float* __restrict__ Wv,   float* __restrict__ out)
{
    __shared__ __align__(16) __bf16 s_h[128 * 256];   // 65536 B (swizzled)
    __shared__ __align__(16) char s_fp[128 * 40 * 2]; // 10240 B: feats, later p
    __bf16* s_f = (__bf16*)s_fp;
    float*  s_p = (float*)s_fp;
    __shared__ float s_mask[128];
    __shared__ float s_qk[8 * 64];
    __shared__ float s_am[8 * 64];
    __shared__ float s_amsum[8];

    const int t  = threadIdx.x;
    const int b0 = blockIdx.x * 2;
    const int wv = t >> 6, lane = t & 63;
    const int lm = lane & 31, lh = lane >> 5;
    const int rtp = wv & 1;
    const int ct0 = (wv >> 1) * 2;
    const int row0 = rtp * 64 + lm;
    const int row1 = row0 + 32;

    // GEMM1 B-fragments: independent of staging, issue before the barrier
    bf16x8 b1[2][2];
    {
        const bf16x8* Bg = (const bf16x8*)wp + S_PW1 * 512;
        #pragma unroll
        for (int kt = 0; kt < 2; ++kt)
            #pragma unroll
            for (int c = 0; c < 2; ++c)
                b1[kt][c] = Bg[(kt * 8 + ct0 + c) * 64 + lane];
    }

    // stage 128 object rows x 32 feats as bf16 (stride 40) + mask col
    {
        const int row = t >> 2, q4 = t & 3;
        const float* src = obs + (size_t)(b0 + (row >> 6)) * OBS_COLS
                               + (row & 63) * 32 + q4 * 8;
        const float4 v0 = ((const float4*)src)[0];
        const float4 v1 = ((const float4*)src)[1];
        bf16x8 o;
        o[0]=(__bf16)v0.x; o[1]=(__bf16)v0.y; o[2]=(__bf16)v0.z; o[3]=(__bf16)v0.w;
        o[4]=(__bf16)v1.x; o[5]=(__bf16)v1.y; o[6]=(__bf16)v1.z; o[7]=(__bf16)v1.w;
        *(bf16x8*)&s_f[row * 40 + q4 * 8] = o;
        if (q4 == 3) s_mask[row] = v1.w;
    }
    // stage qk for both batch rows (coalesced float4)
    if (t < 128) ((float4*)s_qk)[t] = ((const float4*)(qkg + (size_t)b0 * 256))[t];
    __syncthreads();

    f32x16 acc[2][2];
    f32x16 vzero;
    #pragma unroll
    for (int i = 0; i < 16; ++i) vzero[i] = 0.0f;

    // ========== GEMM1: h1 = relu(feats @ W1p + b1), K=32 ==========
    {
        #pragma unroll
        for (int r = 0; r < 2; ++r)
            #pragma unroll
            for (int c = 0; c < 2; ++c) acc[r][c] = vzero;
        #pragma unroll
        for (int kt = 0; kt < 2; ++kt) {
            const bf16x8 a0 = *(const bf16x8*)&s_f[row0 * 40 + kt * 16 + lh * 8];
            const bf16x8 a1 = *(const bf16x8*)&s_f[row1 * 40 + kt * 16 + lh * 8];
            acc[0][0] = __builtin_amdgcn_mfma_f32_32x32x16_bf16(b1[kt][0], a0, acc[0][0], 0, 0, 0);
            acc[0][1] = __builtin_amdgcn_mfma_f32_32x32x16_bf16(b1[kt][1], a0, acc[0][1], 0, 0, 0);
            acc[1][0] = __builtin_amdgcn_mfma_f32_32x32x16_bf16(b1[kt][0], a1, acc[1][0], 0, 0, 0);
            acc[1][1] = __builtin_amdgcn_mfma_f32_32x32x16_bf16(b1[kt][1], a1, acc[1][1], 0, 0, 0);
        }
        #pragma unroll
        for (int r = 0; r < 2; ++r) {
            const int row = r ? row1 : row0;
            #pragma unroll
            for (int c = 0; c < 2; ++c) {
                const float* bias = &pb1[(ct0 + c) * 32 + 4 * lh];
                #pragma unroll
                for (int g = 0; g < 4; ++g) {
                    bf16x4 v;
                    #pragma unroll
                    for (int q = 0; q < 4; ++q)
                        v[q] = (__bf16)fmaxf(acc[r][c][g * 4 + q] + bias[8 * g + q], 0.0f);
                    *(bf16x4*)&s_h[(row << 8) + (((((ct0 + c) << 2) + g) ^ lm) << 3) + 4 * lh] = v;
                }
            }
        }
    }
    __syncthreads();

    // ========== GEMM2: h2 = relu(h1 @ W2 + b2), K=256 ==========
    {
        const bf16x8* Bg = (const bf16x8*)wp + S_PW2 * 512;
        #pragma unroll
        for (int r = 0; r < 2; ++r)
            #pragma unroll
            for (int c = 0; c < 2; ++c) acc[r][c] = vzero;
        bf16x8 bc0 = Bg[(ct0 + 0) * 64 + lane];
        bf16x8 bc1 = Bg[(ct0 + 1) * 64 + lane];
        #pragma unroll 4
        for (int kt = 0; kt < 16; ++kt) {
            const int kn = (kt + 1) & 15;
            const bf16x8 bn0 = Bg[(kn * 8 + ct0 + 0) * 64 + lane];
            const bf16x8 bn1 = Bg[(kn * 8 + ct0 + 1) * 64 + lane];
            const bf16x8 a0 = *(const bf16x8*)&s_h[(row0 << 8) + (((2 * kt + lh) ^ lm) << 3)];
            const bf16x8 a1 = *(const bf16x8*)&s_h[(row1 << 8) + (((2 * kt + lh) ^ lm) << 3)];
            acc[0][0] = __builtin_amdgcn_mfma_f32_32x32x16_bf16(bc0, a0, acc[0][0], 0, 0, 0);
            acc[0][1] = __builtin_amdgcn_mfma_f32_32x32x16_bf16(bc1, a0, acc[0][1], 0, 0, 0);
            acc[1][0] = __builtin_amdgcn_mfma_f32_32x32x16_bf16(bc0, a1, acc[1][0], 0, 0, 0);
            acc[1][1] = __builtin_amdgcn_mfma_f32_32x32x16_bf16(bc1, a1, acc[1][1], 0, 0, 0);
            bc0 = bn0; bc1 = bn1;
        }
        __syncthreads();
        #pragma unroll
        for (int r = 0; r < 2; ++r) {
            const int row = r ? row1 : row0;
            #pragma unroll
            for (int c = 0; c < 2; ++c) {
                const float* bias = &pb2[(ct0 + c) * 32 + 4 * lh];
                #pragma unroll
                for (int g = 0; g < 4; ++g) {
                    bf16x4 v;
                    #pragma unroll
                    for (int q = 0; q < 4; ++q)
                        v[q] = (__bf16)fmaxf(acc[r][c][g * 4 + q] + bias[8 * g + q], 0.0f);
                    *(bf16x4*)&s_h[(row << 8) + (((((ct0 + c) << 2) + g) ^ lm) << 3) + 4 * lh] = v;
                }
            }
        }
    }
    __syncthreads();

    // ========== GEMM3: E = (h2 @ W3 + b3) * mask, K=256 ==========
    {
        const bf16x8* Bg = (const bf16x8*)wp + S_PW3 * 512;
        #pragma unroll
        for (int r = 0; r < 2; ++r)
            #pragma unroll
            for (int c = 0; c < 2; ++c) acc[r][c] = vzero;
        bf16x8 bc0 = Bg[(ct0 + 0) * 64 + lane];
        bf16x8 bc1 = Bg[(ct0 + 1) * 64 + lane];
        #pragma unroll 4
        for (int kt = 0; kt < 16; ++kt) {
            const int kn = (kt + 1) & 15;
            const bf16x8 bn0 = Bg[(kn * 8 + ct0 + 0) * 64 + lane];
            const bf16x8 bn1 = Bg[(kn * 8 + ct0 + 1) * 64 + lane];
            const bf16x8 a0 = *(const bf16x8*)&s_h[(row0 << 8) + (((2 * kt + lh) ^ lm) << 3)];
            const bf16x8 a1 = *(const bf16x8*)&s_h[(row1 << 8) + (((2 * kt + lh) ^ lm) << 3)];
            acc[0][0] = __builtin_amdgcn_mfma_f32_32x32x16_bf16(bc0, a0, acc[0][0], 0, 0, 0);
            acc[0][1] = __builtin_amdgcn_mfma_f32_32x32x16_bf16(bc1, a0, acc[0][1], 0, 0, 0);
            acc[1][0] = __builtin_amdgcn_mfma_f32_32x32x16_bf16(bc0, a1, acc[1][0], 0, 0, 0);
            acc[1][1] = __builtin_amdgcn_mfma_f32_32x32x16_bf16(bc1, a1, acc[1][1], 0, 0, 0);
            bc0 = bn0; bc1 = bn1;
        }
        __syncthreads();
        #pragma unroll
        for (int r = 0; r < 2; ++r) {
            const int row = r ? row1 : row0;
            const float mk = s_mask[row];
            #pragma unroll
            for (int c = 0; c < 2; ++c) {
                const float* bias = &pb3[(ct0 + c) * 32 + 4 * lh];
                #pragma unroll
                for (int g = 0; g < 4; ++g) {
                    bf16x4 v;
                    #pragma unroll
                    for (int q = 0; q < 4; ++q)
                        v[q] = (__bf16)((acc[r][c][g * 4 + q] + bias[8 * g + q]) * mk);
                    *(bf16x4*)&s_h[(row << 8) + (((((ct0 + c) << 2) + g) ^ lm) << 3) + 4 * lh] = v;
                }
            }
        }
    }
    __syncthreads();

    // ---- Phase B: logits + softmax (wave = one (r,h) unit; lane = object) ----
    {
        const int r = wv >> 2, h = wv & 3;
        const float qb = qbg[(size_t)(b0 + r) * 4 + h];
        const int erow = r * 64 + lane;
        float dot = 0.0f;
        #pragma unroll
        for (int d8 = 0; d8 < 8; ++d8) {
            const bf16x8 ev = *(const bf16x8*)&s_h[(erow << 8) + ((((h << 3) + d8) ^ (erow & 31)) << 3)];
            const float* kv = &s_qk[(r * 4 + h) * 64 + d8 * 8];
            #pragma unroll
            for (int j = 0; j < 8; ++j) dot += (float)ev[j] * kv[j];
        }
        const float mk = s_mask[erow];
        float logit = (dot + qb) * 0.0625f;
        if (mk == 0.0f) logit = -1.0e9f;
        float m = logit;
        #pragma unroll
        for (int off = 32; off > 0; off >>= 1) m = fmaxf(m, __shfl_xor(m, off, 64));
        const float ex = __expf(logit - m);
        float ssum = ex;
        #pragma unroll
        for (int off = 32; off > 0; off >>= 1) ssum += __shfl_xor(ssum, off, 64);
        const float am = (ex / ssum) * mk;
        s_am[(r * 4 + h) * 64 + lane] = am;
        float ams = am;
        #pragma unroll
        for (int off = 32; off > 0; off >>= 1) ams += __shfl_xor(ams, off, 64);
        if (lane == 0) s_amsum[r * 4 + h] = ams;
    }
    __syncthreads();

    // ---- Phase C: p[r][h][d] = sum_n am * E[n][h*64+d] -> s_p ----
    {
        const int r = t >> 8, h = (t >> 6) & 3, d = t & 63;
        const float* amr = &s_am[(r * 4 + h) * 64];
        const int blkbase = (h << 3) + (d >> 3);
        const int doff = d & 7;
        float a = 0.0f;
        #pragma unroll 16
        for (int n = 0; n < 64; ++n) {
            const int row = r * 64 + n;
            a += amr[n] * (float)s_h[(row << 8) + (((blkbase ^ (row & 31)) << 3) | doff)];
        }
        s_p[(r * 4 + h) * 64 + d] = a;
    }
    __syncthreads();

    // ---- Phase D: out_emb = p @ Wv + amsum * bv ----
    {
        const int r = t >> 8, h = (t >> 6) & 3, e = t & 63;
        float a = s_amsum[r * 4 + h] * bv[h * 64 + e];
        const float* pr  = &s_p[(r * 4 + h) * 64];
        const float* wvp = Wv + (size_t)h * 64 * 64 + e;
        #pragma unroll 16
        for (int d = 0; d < 64; ++d)
            a += pr[d] * wvp[d * 64];
        out[(size_t)(b0 + r) * OUTC + EMB + h * 64 + e] = a;
    }
}

extern "C" void kernel_launch(void* const* d_in, const int* in_sizes, int n_in,
                              void* d_out, int out_size, void* d_ws, size_t ws_size,
                              hipStream_t stream)
{
    const float* obs = (const float*)d_in[0];
    const float* oW1 = (const float*)d_in[1];
    const float* ob1 = (const float*)d_in[2];
    const float* oW2 = (const float*)d_in[3];
    const float* ob2 = (const float*)d_in[4];
    const float* pW1 = (const float*)d_in[5];
    const float* pb1 = (const float*)d_in[6];
    const float* pW2 = (const float*)d_in[7];
    const float* pb2 = (const float*)d_in[8];
    const float* pW3 = (const float*)d_in[9];
    const float* pb3 = (const float*)d_in[10];
    const float* Wq  = (const float*)d_in[11];
    const float* bq  = (const float*)d_in[12];
    const float* Wk  = (const float*)d_in[13];
    const float* bk  = (const float*)d_in[14];
    const float* Wv  = (const float*)d_in[15];
    const float* bv  = (const float*)d_in[16];
    float*  out = (float*)d_out;
    float*  qkg = (float*)d_ws;
    float*  qbg = (float*)((char*)d_ws + QK_BYTES);
    __bf16* wp  = (__bf16*)((char*)d_ws + QK_BYTES + QB_BYTES);

    k_oth<<<BATCH / 32, 512, 0, stream>>>(obs, oW1, ob1, oW2, ob2, Wq, bq,
                                          Wk, bk, pW1, pW2, pW3,
                                          out, qkg, qbg, wp);
    k_obj<<<BATCH / 2, 512, 0, stream>>>(obs, wp, pb1, pb2, pb3, qkg, qbg,
                                         bv, Wv, out);
}